// Round 1
// baseline (8103.075 us; speedup 1.0000x reference)
//
#include <hip/hip_runtime.h>
#include <cstdint>
#include <cstddef>

#define CDIM 1024
#define HN 16
#define HD 64
#define WINSZ 512
#define SHIFTSZ 256
#define TK 16
#define HIDDIM 4096
#define LSEQ 4096
#define NCOL9 9216
#define LCTX 1024

// ---------------------------------------------------------------------------
// m = silu(mod) @ w_ada + b_ada      (2 x 9216)
// ---------------------------------------------------------------------------
__global__ __launch_bounds__(256)
void k_mod_ada(const float* __restrict__ mod, const float* __restrict__ w_ada,
               const float* __restrict__ b_ada, float* __restrict__ m_out) {
  __shared__ float sm[CDIM];
  int b = blockIdx.y;
  int t = threadIdx.x;
  for (int k = t; k < CDIM; k += 256) {
    float v = mod[b * CDIM + k];
    sm[k] = v / (1.f + __expf(-v));
  }
  __syncthreads();
  int j = blockIdx.x * 256 + t;
  float acc = b_ada[j];
  for (int k = 0; k < CDIM; ++k) acc += sm[k] * w_ada[(size_t)k * NCOL9 + j];
  m_out[b * NCOL9 + j] = acc;
}

// ---------------------------------------------------------------------------
// h = ln(x) * (1 + sc) + sh   (one block per row)
// ---------------------------------------------------------------------------
__global__ __launch_bounds__(256)
void k_ln_mod(const float* __restrict__ x, const float* __restrict__ mbuf,
              float* __restrict__ h, int shsel, int scsel) {
  __shared__ float ws1[4], ws2[4], sstat[2];
  int row = blockIdx.x;
  int b = row >> 12;
  int t = threadIdx.x;
  const float4* xr = (const float4*)(x + (size_t)row * CDIM);
  float4 v = xr[t];
  float s1 = v.x + v.y + v.z + v.w;
  float s2 = v.x * v.x + v.y * v.y + v.z * v.z + v.w * v.w;
  for (int off = 32; off; off >>= 1) {
    s1 += __shfl_down(s1, off);
    s2 += __shfl_down(s2, off);
  }
  int wid = t >> 6, lane = t & 63;
  if (lane == 0) { ws1[wid] = s1; ws2[wid] = s2; }
  __syncthreads();
  if (t == 0) {
    float a = 0.f, c = 0.f;
    for (int i = 0; i < 4; ++i) { a += ws1[i]; c += ws2[i]; }
    float mean = a * (1.f / CDIM);
    float var = c * (1.f / CDIM) - mean * mean;
    sstat[0] = mean;
    sstat[1] = rsqrtf(var + 1e-6f);
  }
  __syncthreads();
  float mean = sstat[0], rstd = sstat[1];
  const float* sc = mbuf + b * NCOL9 + scsel * CDIM;
  const float* sh = mbuf + b * NCOL9 + shsel * CDIM;
  int c0 = t * 4;
  float4 o;
  o.x = (v.x - mean) * rstd * (1.f + sc[c0 + 0]) + sh[c0 + 0];
  o.y = (v.y - mean) * rstd * (1.f + sc[c0 + 1]) + sh[c0 + 1];
  o.z = (v.z - mean) * rstd * (1.f + sc[c0 + 2]) + sh[c0 + 2];
  o.w = (v.w - mean) * rstd * (1.f + sc[c0 + 3]) + sh[c0 + 3];
  ((float4*)(h + (size_t)row * CDIM))[t] = o;
}

// ---------------------------------------------------------------------------
// Tiled fp32 GEMM: out = A[M,K] @ W[K,N] + bias, with optional fused
// residual epilogue: out = xres + (acc + bias) * g[b, n]
// 128x128 tile, BK=16, 256 threads, 8x8 per thread, double-buffered LDS.
// ---------------------------------------------------------------------------
#define BM 128
#define BN 128
#define BK 16

template <int EPI>
__global__ __launch_bounds__(256)
void k_gemm(const float* __restrict__ A, const float* __restrict__ W,
            const float* __restrict__ bias, float* __restrict__ out,
            const float* __restrict__ xres, const float* __restrict__ mbuf,
            int M, int N, int K, int gsel, int row0) {
  __shared__ float As[2][BK][BM + 4];
  __shared__ float Bs[2][BK][BN];
  int t = threadIdx.x;
  int bm = blockIdx.y, bn = blockIdx.x;
  int tx = t & 15, ty = t >> 4;

  const float* Abase = A + (size_t)(bm * BM) * K;
  const float* Wbase = W + bn * BN;

  int ar0 = t >> 2, ac = (t & 3) * 4;      // A tile: 128 rows x 16 cols
  int br0 = t >> 5, bc = (t & 31) * 4;     // B tile: 16 rows x 128 cols

  float acc[8][8];
#pragma unroll
  for (int i = 0; i < 8; ++i)
#pragma unroll
    for (int j = 0; j < 8; ++j) acc[i][j] = 0.f;

  float4 a0, a1, b0, b1;
  auto loadG = [&](int kt) {
    a0 = *(const float4*)(Abase + (size_t)ar0 * K + kt * BK + ac);
    a1 = *(const float4*)(Abase + (size_t)(ar0 + 64) * K + kt * BK + ac);
    b0 = *(const float4*)(Wbase + (size_t)(kt * BK + br0) * N + bc);
    b1 = *(const float4*)(Wbase + (size_t)(kt * BK + br0 + 8) * N + bc);
  };
  auto storeL = [&](int buf) {
    As[buf][ac + 0][ar0] = a0.x; As[buf][ac + 1][ar0] = a0.y;
    As[buf][ac + 2][ar0] = a0.z; As[buf][ac + 3][ar0] = a0.w;
    As[buf][ac + 0][ar0 + 64] = a1.x; As[buf][ac + 1][ar0 + 64] = a1.y;
    As[buf][ac + 2][ar0 + 64] = a1.z; As[buf][ac + 3][ar0 + 64] = a1.w;
    *(float4*)&Bs[buf][br0][bc] = b0;
    *(float4*)&Bs[buf][br0 + 8][bc] = b1;
  };

  loadG(0);
  storeL(0);
  __syncthreads();
  int nk = K / BK;
  for (int kt = 0; kt < nk; ++kt) {
    int cur = kt & 1;
    if (kt + 1 < nk) loadG(kt + 1);
#pragma unroll
    for (int k = 0; k < BK; ++k) {
      float av[8], bv[8];
      *(float4*)&av[0] = *(const float4*)&As[cur][k][ty * 8];
      *(float4*)&av[4] = *(const float4*)&As[cur][k][ty * 8 + 4];
      *(float4*)&bv[0] = *(const float4*)&Bs[cur][k][tx * 8];
      *(float4*)&bv[4] = *(const float4*)&Bs[cur][k][tx * 8 + 4];
#pragma unroll
      for (int i = 0; i < 8; ++i)
#pragma unroll
        for (int j = 0; j < 8; ++j) acc[i][j] += av[i] * bv[j];
    }
    if (kt + 1 < nk) {
      storeL(cur ^ 1);
      __syncthreads();
    }
  }

  int orow = bm * BM + ty * 8;
  int ocol = bn * BN + tx * 8;
#pragma unroll
  for (int i = 0; i < 8; ++i) {
    float ov[8];
#pragma unroll
    for (int j = 0; j < 8; ++j) ov[j] = acc[i][j] + bias[ocol + j];
    size_t idx = (size_t)(orow + i) * N + ocol;
    if (EPI == 1) {
      int bb = (row0 + orow + i) >> 12;
      const float* g = mbuf + bb * NCOL9 + gsel * CDIM;
#pragma unroll
      for (int j = 0; j < 8; ++j) ov[j] = xres[idx + j] + ov[j] * g[ocol + j];
    }
    *(float4*)(out + idx) = *(float4*)&ov[0];
    *(float4*)(out + idx + 4) = *(float4*)&ov[4];
  }
}

// ---------------------------------------------------------------------------
// Windowed shifted self-attention. One 512-thread block per (b, window, head);
// thread = one q row; K/V chunks of 128 staged in LDS; online softmax.
// Roll(-SHIFT) folded into index: position p = (w*512 + j + 256) mod 4096,
// and the output roll(+SHIFT) writes back to the same p.
// ---------------------------------------------------------------------------
__global__ __launch_bounds__(512, 1)
void k_self_attn(const float* __restrict__ qkv, float* __restrict__ o_buf) {
  __shared__ float Ks[128][HD];
  __shared__ float Vs[128][HD];
  int blk = blockIdx.x;  // b(2) x w(8) x h(16)
  int b = blk >> 7;
  int w = (blk >> 4) & 7;
  int h = blk & 15;
  int t = threadIdx.x;

  int p = (w * WINSZ + t + SHIFTSZ) & (LSEQ - 1);
  const float* qrow = qkv + ((size_t)(b * LSEQ + p)) * 3072 + h * HD;
  float q[HD];
#pragma unroll
  for (int i = 0; i < 16; ++i) *(float4*)&q[i * 4] = *(const float4*)(qrow + i * 4);

  float o[HD];
#pragma unroll
  for (int d = 0; d < HD; ++d) o[d] = 0.f;
  float mrun = -1e30f, lrun = 0.f;

  for (int kc = 0; kc < 4; ++kc) {
    __syncthreads();
#pragma unroll
    for (int i = 0; i < 4; ++i) {
      int f = t + i * 512;              // 0..2047 : 128 rows x 16 float4
      int r = f >> 4, c4 = (f & 15) * 4;
      int pk = (w * WINSZ + kc * 128 + r + SHIFTSZ) & (LSEQ - 1);
      const float* src = qkv + ((size_t)(b * LSEQ + pk)) * 3072 + h * HD;
      *(float4*)&Ks[r][c4] = *(const float4*)(src + CDIM + c4);
      *(float4*)&Vs[r][c4] = *(const float4*)(src + 2 * CDIM + c4);
    }
    __syncthreads();
    for (int j = 0; j < 128; ++j) {
      float s = 0.f;
#pragma unroll
      for (int d = 0; d < HD; ++d) s += q[d] * Ks[j][d];
      s *= 0.125f;
      if (s <= mrun) {
        float pe = __expf(s - mrun);
        lrun += pe;
#pragma unroll
        for (int d = 0; d < HD; ++d) o[d] += pe * Vs[j][d];
      } else {                           // rare after warmup
        float corr = __expf(mrun - s);
        mrun = s;
        lrun = lrun * corr + 1.f;
#pragma unroll
        for (int d = 0; d < HD; ++d) o[d] = o[d] * corr + Vs[j][d];
      }
    }
  }
  float inv = 1.f / lrun;
  float* op = o_buf + ((size_t)(b * LSEQ + p)) * CDIM + h * HD;
#pragma unroll
  for (int i = 0; i < 16; ++i) {
    float4 v;
    v.x = o[i * 4] * inv; v.y = o[i * 4 + 1] * inv;
    v.z = o[i * 4 + 2] * inv; v.w = o[i * 4 + 3] * inv;
    *(float4*)(op + i * 4) = v;
  }
}

// ---------------------------------------------------------------------------
// Cross-attn scores + streaming top-16 (stable ties = earlier index wins,
// matching lax.top_k). Register-resident sorted list, static indexing only.
// ---------------------------------------------------------------------------
__global__ __launch_bounds__(256)
void k_cross_topk(const float* __restrict__ qb, const float* __restrict__ kvb,
                  float* __restrict__ topS, int* __restrict__ topI) {
  __shared__ float Ks[128][HD];
  int qc = blockIdx.x, h = blockIdx.y, b = blockIdx.z;
  int t = threadIdx.x;

  int qrow = qc * 256 + t;
  const float* qp = qb + ((size_t)(b * LSEQ + qrow)) * CDIM + h * HD;
  float q[HD];
#pragma unroll
  for (int i = 0; i < 16; ++i) *(float4*)&q[i * 4] = *(const float4*)(qp + i * 4);

  float s16[TK];
  int i16[TK];
#pragma unroll
  for (int i = 0; i < TK; ++i) { s16[i] = -1e30f; i16[i] = 0; }
  float smin = -1e30f;

  for (int kc = 0; kc < 8; ++kc) {
    __syncthreads();
#pragma unroll
    for (int i = 0; i < 8; ++i) {
      int f = t + i * 256;              // 0..2047
      int r = f >> 4, c4 = (f & 15) * 4;
      *(float4*)&Ks[r][c4] =
          *(const float4*)(kvb + ((size_t)(b * LCTX + kc * 128 + r)) * 2048 + h * HD + c4);
    }
    __syncthreads();
    for (int j = 0; j < 128; ++j) {
      float s = 0.f;
#pragma unroll
      for (int d = 0; d < HD; ++d) s += q[d] * Ks[j][d];
      s *= 0.125f;
      if (s > smin) {
        int kidx = kc * 128 + j;
#pragma unroll
        for (int i = TK - 1; i >= 1; --i) {
          float up = s16[i - 1];
          if (up < s) { s16[i] = up; i16[i] = i16[i - 1]; }
          else if (s16[i] < s) { s16[i] = s; i16[i] = kidx; }
        }
        if (s16[0] < s) { s16[0] = s; i16[0] = kidx; }
        smin = s16[TK - 1];
      }
    }
  }
  size_t rbase = ((size_t)((b * HN + h) * LSEQ + qrow)) * TK;
#pragma unroll
  for (int i = 0; i < TK; ++i) { topS[rbase + i] = s16[i]; topI[rbase + i] = i16[i]; }
}

// ---------------------------------------------------------------------------
// Softmax over top-16 + V gather. One wave per (b,h,q) row; lane = d.
// ---------------------------------------------------------------------------
__global__ __launch_bounds__(256)
void k_cross_gather(const float* __restrict__ topS, const int* __restrict__ topI,
                    const float* __restrict__ kvb, float* __restrict__ o2) {
  int t = threadIdx.x;
  int wid = t >> 6, lane = t & 63;
  int r = blockIdx.x * 4 + wid;        // 0..131071 = (b*16+h)*4096+q
  int b = r >> 16;
  int h = (r >> 12) & 15;
  int q = r & 4095;
  const float* sp = topS + (size_t)r * TK;
  const int* ip = topI + (size_t)r * TK;
  float sv[TK], pv[TK];
  int iv[TK];
#pragma unroll
  for (int i = 0; i < TK; ++i) { sv[i] = sp[i]; iv[i] = ip[i]; }
  float mx = sv[0];                    // sorted descending
  float sum = 0.f;
#pragma unroll
  for (int i = 0; i < TK; ++i) { pv[i] = __expf(sv[i] - mx); sum += pv[i]; }
  float inv = 1.f / sum;
  float acc = 0.f;
#pragma unroll
  for (int i = 0; i < TK; ++i)
    acc += pv[i] * kvb[((size_t)(b * LCTX + iv[i])) * 2048 + CDIM + h * HD + lane];
  o2[((size_t)(b * LSEQ + q)) * CDIM + h * HD + lane] = acc * inv;
}

// ---------------------------------------------------------------------------
// g = silu(u[:, :HID]) * u[:, HID:]
// ---------------------------------------------------------------------------
__global__ __launch_bounds__(256)
void k_silu_mul(const float* __restrict__ U, float* __restrict__ G, int rows) {
  int id = blockIdx.x * 256 + threadIdx.x;
  int total = rows * (HIDDIM / 4);
  if (id >= total) return;
  int row = id >> 10;                  // HID/4 = 1024 float4 per row
  int c4 = id & 1023;
  const float4* ua = (const float4*)U + (size_t)row * (2 * HIDDIM / 4) + c4;
  float4 a = *ua;
  float4 bb = *(ua + HIDDIM / 4);
  float4 g;
  g.x = a.x / (1.f + __expf(-a.x)) * bb.x;
  g.y = a.y / (1.f + __expf(-a.y)) * bb.y;
  g.z = a.z / (1.f + __expf(-a.z)) * bb.z;
  g.w = a.w / (1.f + __expf(-a.w)) * bb.w;
  ((float4*)G)[(size_t)row * (HIDDIM / 4) + c4] = g;
}

// ---------------------------------------------------------------------------
extern "C" void kernel_launch(void* const* d_in, const int* in_sizes, int n_in,
                              void* d_out, int out_size, void* d_ws, size_t ws_size,
                              hipStream_t stream) {
  const float* x0    = (const float*)d_in[0];
  const float* mod   = (const float*)d_in[1];
  const float* ctx   = (const float*)d_in[2];
  const float* w_ada = (const float*)d_in[3];
  const float* b_ada = (const float*)d_in[4];
  const float* w_qkv = (const float*)d_in[5];
  const float* b_qkv = (const float*)d_in[6];
  const float* w_so  = (const float*)d_in[7];
  const float* b_so  = (const float*)d_in[8];
  const float* w_q   = (const float*)d_in[9];
  const float* b_q   = (const float*)d_in[10];
  const float* w_kv  = (const float*)d_in[11];
  const float* b_kv  = (const float*)d_in[12];
  const float* w_co  = (const float*)d_in[13];
  const float* b_co  = (const float*)d_in[14];
  const float* w_m1  = (const float*)d_in[15];
  const float* b_m1  = (const float*)d_in[16];
  const float* w_m2  = (const float*)d_in[17];
  const float* b_m2  = (const float*)d_in[18];
  float* out = (float*)d_out;

  float* ws   = (float*)d_ws;
  float* mb   = ws;                    // 18432
  float* hbuf = mb + 18432;            // 8388608   LN output
  float* s1   = hbuf + 8388608;        // 25165824  qkv / topk / U
  float* s2   = s1 + 25165824;         // 8388608   o / o2 / G
  float* s3   = s2 + 8388608;          // 8388608   q
  float* s4   = s3 + 8388608;          // 4194304   kv
  float* xb   = s4 + 4194304;          // 8388608   running residual X
  // total: 62,932,992 floats = 251.7 MB

  // 1. modulation vector
  k_mod_ada<<<dim3(36, 2), 256, 0, stream>>>(mod, w_ada, b_ada, mb);
  // 2. LN1 + (sh_msa, sc_msa)
  k_ln_mod<<<8192, 256, 0, stream>>>(x0, mb, hbuf, 0, 1);
  // 3. qkv projection
  k_gemm<0><<<dim3(24, 64), 256, 0, stream>>>(hbuf, w_qkv, b_qkv, s1, nullptr, nullptr,
                                              8192, 3072, 1024, 0, 0);
  // 4. windowed self-attention
  k_self_attn<<<256, 512, 0, stream>>>(s1, s2);
  // 5. output proj + residual: X = x0 + (o@w_so + b)*g_msa
  k_gemm<1><<<dim3(8, 64), 256, 0, stream>>>(s2, w_so, b_so, xb, x0, mb,
                                             8192, 1024, 1024, 2, 0);
  // 6. LN2 + (sh_mca, sc_mca)
  k_ln_mod<<<8192, 256, 0, stream>>>(xb, mb, hbuf, 3, 4);
  // 7. q projection
  k_gemm<0><<<dim3(8, 64), 256, 0, stream>>>(hbuf, w_q, b_q, s3, nullptr, nullptr,
                                             8192, 1024, 1024, 0, 0);
  // 8. kv projection (raw context, no LN)
  k_gemm<0><<<dim3(16, 16), 256, 0, stream>>>(ctx, w_kv, b_kv, s4, nullptr, nullptr,
                                              2048, 2048, 1024, 0, 0);
  // 9. cross-attn scores + top-16
  float* topS = s1;
  int* topI = (int*)(s1 + 2097152);
  k_cross_topk<<<dim3(16, 16, 2), 256, 0, stream>>>(s3, s4, topS, topI);
  // 10. softmax + gather
  k_cross_gather<<<32768, 256, 0, stream>>>(topS, topI, s4, s2);
  // 11. co proj + residual (in-place X)
  k_gemm<1><<<dim3(8, 64), 256, 0, stream>>>(s2, w_co, b_co, xb, xb, mb,
                                             8192, 1024, 1024, 5, 0);
  // 12. LN3 + (sh_mlp, sc_mlp)
  k_ln_mod<<<8192, 256, 0, stream>>>(xb, mb, hbuf, 6, 7);
  // 13. swiglu, chunked over M (4 x 2048 rows)
  for (int ch = 0; ch < 4; ++ch) {
    const float* hA = hbuf + (size_t)ch * 2048 * 1024;
    k_gemm<0><<<dim3(64, 16), 256, 0, stream>>>(hA, w_m1, b_m1, s1, nullptr, nullptr,
                                                2048, 8192, 1024, 0, 0);
    k_silu_mul<<<8192, 256, 0, stream>>>(s1, s2, 2048);
    k_gemm<1><<<dim3(8, 16), 256, 0, stream>>>(s2, w_m2, b_m2,
                                               out + (size_t)ch * 2048 * 1024,
                                               xb + (size_t)ch * 2048 * 1024, mb,
                                               2048, 1024, 4096, 8, ch * 2048);
  }
}

// Round 2
// 2617.632 us; speedup vs baseline: 3.0956x; 3.0956x over previous
//
#include <hip/hip_runtime.h>
#include <cstdint>
#include <cstddef>

#define CDIM 1024
#define HN 16
#define HD 64
#define WINSZ 512
#define SHIFTSZ 256
#define TK 16
#define HIDDIM 4096
#define LSEQ 4096
#define NCOL9 9216
#define LCTX 1024

typedef __bf16 bf16x8 __attribute__((ext_vector_type(8)));
typedef float f32x4 __attribute__((ext_vector_type(4)));

static __device__ __forceinline__ unsigned short f2bf(float f) {
  unsigned u = __float_as_uint(f);
  unsigned r = (u + 0x7fffu + ((u >> 16) & 1u)) >> 16;
  return (unsigned short)r;
}

// ---------------------------------------------------------------------------
// m = silu(mod) @ w_ada + b_ada      (2 x 9216)
// ---------------------------------------------------------------------------
__global__ __launch_bounds__(256)
void k_mod_ada(const float* __restrict__ mod, const float* __restrict__ w_ada,
               const float* __restrict__ b_ada, float* __restrict__ m_out) {
  __shared__ float sm[CDIM];
  int b = blockIdx.y;
  int t = threadIdx.x;
  for (int k = t; k < CDIM; k += 256) {
    float v = mod[b * CDIM + k];
    sm[k] = v / (1.f + __expf(-v));
  }
  __syncthreads();
  int j = blockIdx.x * 256 + t;
  float acc = b_ada[j];
#pragma unroll 8
  for (int k = 0; k < CDIM; ++k) acc += sm[k] * w_ada[(size_t)k * NCOL9 + j];
  m_out[b * NCOL9 + j] = acc;
}

// ---------------------------------------------------------------------------
// Weight transpose + cast: W[K][N] fp32 -> WT[N][K] bf16 bits
// ---------------------------------------------------------------------------
__global__ __launch_bounds__(256)
void k_wt(const float* __restrict__ W, unsigned short* __restrict__ WT,
          int K, int N) {
  __shared__ float tl[32][33];
  int tx = threadIdx.x & 31, ty = threadIdx.x >> 5;
  int n0 = blockIdx.x * 32, k0 = blockIdx.y * 32;
#pragma unroll
  for (int i = 0; i < 4; ++i)
    tl[ty + i * 8][tx] = W[(size_t)(k0 + ty + i * 8) * N + n0 + tx];
  __syncthreads();
#pragma unroll
  for (int i = 0; i < 4; ++i) {
    int n = ty + i * 8;
    WT[(size_t)(n0 + n) * K + k0 + tx] = f2bf(tl[tx][n]);
  }
}

// fp32 -> bf16 elementwise (context)
__global__ __launch_bounds__(256)
void k_cast_bf(const float* __restrict__ in, unsigned short* __restrict__ o, int n4) {
  int id = blockIdx.x * 256 + threadIdx.x;
  if (id >= n4) return;
  float4 v = ((const float4*)in)[id];
  ushort4 u;
  u.x = f2bf(v.x); u.y = f2bf(v.y); u.z = f2bf(v.z); u.w = f2bf(v.w);
  ((ushort4*)o)[id] = u;
}

// ---------------------------------------------------------------------------
// h = ln(x) * (1 + sc) + sh  -> bf16   (one block per row)
// ---------------------------------------------------------------------------
__global__ __launch_bounds__(256)
void k_ln_mod(const float* __restrict__ x, const float* __restrict__ mbuf,
              unsigned short* __restrict__ h, int shsel, int scsel) {
  __shared__ float ws1[4], ws2[4], sstat[2];
  int row = blockIdx.x;
  int b = row >> 12;
  int t = threadIdx.x;
  const float4* xr = (const float4*)(x + (size_t)row * CDIM);
  float4 v = xr[t];
  float s1 = v.x + v.y + v.z + v.w;
  float s2 = v.x * v.x + v.y * v.y + v.z * v.z + v.w * v.w;
  for (int off = 32; off; off >>= 1) {
    s1 += __shfl_down(s1, off);
    s2 += __shfl_down(s2, off);
  }
  int wid = t >> 6, lane = t & 63;
  if (lane == 0) { ws1[wid] = s1; ws2[wid] = s2; }
  __syncthreads();
  if (t == 0) {
    float a = 0.f, c = 0.f;
    for (int i = 0; i < 4; ++i) { a += ws1[i]; c += ws2[i]; }
    float mean = a * (1.f / CDIM);
    float var = c * (1.f / CDIM) - mean * mean;
    sstat[0] = mean;
    sstat[1] = rsqrtf(var + 1e-6f);
  }
  __syncthreads();
  float mean = sstat[0], rstd = sstat[1];
  const float* sc = mbuf + b * NCOL9 + scsel * CDIM;
  const float* sh = mbuf + b * NCOL9 + shsel * CDIM;
  int c0 = t * 4;
  ushort4 u;
  u.x = f2bf((v.x - mean) * rstd * (1.f + sc[c0 + 0]) + sh[c0 + 0]);
  u.y = f2bf((v.y - mean) * rstd * (1.f + sc[c0 + 1]) + sh[c0 + 1]);
  u.z = f2bf((v.z - mean) * rstd * (1.f + sc[c0 + 2]) + sh[c0 + 2]);
  u.w = f2bf((v.w - mean) * rstd * (1.f + sc[c0 + 3]) + sh[c0 + 3]);
  *(ushort4*)(h + (size_t)row * CDIM + c0) = u;
}

// ---------------------------------------------------------------------------
// bf16 MFMA GEMM: out[M][N] = Abf[M][K] @ WT[N][K]^T + bias  (fp32 out)
// EPI=1: out = xres + (acc + bias) * g[b, n]
// 128x128 tile, BK=32, 4 waves (2x2), 16x16x32 MFMA, global_load_lds(16B),
// slot-XOR LDS swizzle (source-side pre-swizzle + swizzled ds_read).
// ---------------------------------------------------------------------------
template <int EPI>
__global__ __launch_bounds__(256)
void k_gemm_bf(const unsigned short* __restrict__ Ab,
               const unsigned short* __restrict__ Bt,
               const float* __restrict__ bias, float* __restrict__ out,
               const float* __restrict__ xres, const float* __restrict__ mbuf,
               int M, int N, int K, int gsel, int row0) {
  __shared__ unsigned short lsA[128 * 32];
  __shared__ unsigned short lsB[128 * 32];
  int t = threadIdx.x;
  int bm = blockIdx.y, bn = blockIdx.x;
  int l = t & 63, wv = t >> 6;
  int wm = wv >> 1, wn = wv & 1;
  int lane15 = l & 15, hw = l >> 4;

  // staging: 2 chunks of 16B per thread per matrix per K-tile
  int d0 = t, d1 = t + 256;
  int r0 = d0 >> 2, sl0 = (d0 & 3) ^ ((d0 >> 3) & 3);
  int r1 = d1 >> 2, sl1 = (d1 & 3) ^ ((d1 >> 3) & 3);
  const unsigned short* a_src0 = Ab + (size_t)(bm * 128 + r0) * K + sl0 * 8;
  const unsigned short* a_src1 = Ab + (size_t)(bm * 128 + r1) * K + sl1 * 8;
  const unsigned short* b_src0 = Bt + (size_t)(bn * 128 + r0) * K + sl0 * 8;
  const unsigned short* b_src1 = Bt + (size_t)(bn * 128 + r1) * K + sl1 * 8;

  f32x4 acc[4][4];
#pragma unroll
  for (int i = 0; i < 4; ++i)
#pragma unroll
    for (int j = 0; j < 4; ++j) acc[i][j] = (f32x4){0.f, 0.f, 0.f, 0.f};

  auto stage = [&](int kt) {
    int ko = kt * 32;
    __builtin_amdgcn_global_load_lds(
        (const __attribute__((address_space(1))) void*)(a_src0 + ko),
        (__attribute__((address_space(3))) void*)(lsA + d0 * 8), 16, 0, 0);
    __builtin_amdgcn_global_load_lds(
        (const __attribute__((address_space(1))) void*)(a_src1 + ko),
        (__attribute__((address_space(3))) void*)(lsA + d1 * 8), 16, 0, 0);
    __builtin_amdgcn_global_load_lds(
        (const __attribute__((address_space(1))) void*)(b_src0 + ko),
        (__attribute__((address_space(3))) void*)(lsB + d0 * 8), 16, 0, 0);
    __builtin_amdgcn_global_load_lds(
        (const __attribute__((address_space(1))) void*)(b_src1 + ko),
        (__attribute__((address_space(3))) void*)(lsB + d1 * 8), 16, 0, 0);
  };

  stage(0);

  // fragment read addresses (bytes), with slot-XOR swizzle
  int swz = ((lane15 >> 1) & 3) << 4;
  int aoff = (wm * 64 + lane15) * 64 + (((hw << 4) ^ swz));
  int boff = (wn * 64 + lane15) * 64 + (((hw << 4) ^ swz));

  int nk = K >> 5;
  for (int kt = 0; kt < nk; ++kt) {
    __syncthreads();  // staged tile visible
    bf16x8 af[4], bfr[4];
#pragma unroll
    for (int i = 0; i < 4; ++i) {
      af[i]  = *reinterpret_cast<const bf16x8*>((const char*)lsA + aoff + i * 1024);
      bfr[i] = *reinterpret_cast<const bf16x8*>((const char*)lsB + boff + i * 1024);
    }
#pragma unroll
    for (int mi = 0; mi < 4; ++mi)
#pragma unroll
      for (int ni = 0; ni < 4; ++ni)
        acc[mi][ni] = __builtin_amdgcn_mfma_f32_16x16x32_bf16(
            af[mi], bfr[ni], acc[mi][ni], 0, 0, 0);
    __syncthreads();  // reads done before overwrite
    if (kt + 1 < nk) stage(kt + 1);
  }

  const float* g = nullptr;
  if (EPI) g = mbuf + ((size_t)((row0 + bm * 128) >> 12)) * NCOL9 + gsel * CDIM;
#pragma unroll
  for (int ni = 0; ni < 4; ++ni) {
    int gcol = bn * 128 + wn * 64 + ni * 16 + lane15;
    float bs = bias[gcol];
    float gg = EPI ? g[gcol] : 0.f;
#pragma unroll
    for (int mi = 0; mi < 4; ++mi) {
      int grow0 = bm * 128 + wm * 64 + mi * 16 + hw * 4;
      f32x4 v = acc[mi][ni];
#pragma unroll
      for (int rr = 0; rr < 4; ++rr) {
        size_t idx = (size_t)(grow0 + rr) * N + gcol;
        float ov = v[rr] + bs;
        if (EPI) ov = xres[idx] + ov * gg;
        out[idx] = ov;
      }
    }
  }
}

// ---------------------------------------------------------------------------
// Windowed shifted self-attention (fp32 math, bf16 output).
// One 512-thread block per (b, window, head); thread = one q row.
// ---------------------------------------------------------------------------
__global__ __launch_bounds__(512, 1)
void k_self_attn(const float* __restrict__ qkv, unsigned short* __restrict__ o_buf) {
  __shared__ float Ks[128][HD];
  __shared__ float Vs[128][HD];
  int blk = blockIdx.x;  // b(2) x w(8) x h(16)
  int b = blk >> 7;
  int w = (blk >> 4) & 7;
  int h = blk & 15;
  int t = threadIdx.x;

  int p = (w * WINSZ + t + SHIFTSZ) & (LSEQ - 1);
  const float* qrow = qkv + ((size_t)(b * LSEQ + p)) * 3072 + h * HD;
  float q[HD];
#pragma unroll
  for (int i = 0; i < 16; ++i) *(float4*)&q[i * 4] = *(const float4*)(qrow + i * 4);

  float o[HD];
#pragma unroll
  for (int d = 0; d < HD; ++d) o[d] = 0.f;
  float mrun = -1e30f, lrun = 0.f;

  for (int kc = 0; kc < 4; ++kc) {
    __syncthreads();
#pragma unroll
    for (int i = 0; i < 4; ++i) {
      int f = t + i * 512;
      int r = f >> 4, c4 = (f & 15) * 4;
      int pk = (w * WINSZ + kc * 128 + r + SHIFTSZ) & (LSEQ - 1);
      const float* src = qkv + ((size_t)(b * LSEQ + pk)) * 3072 + h * HD;
      *(float4*)&Ks[r][c4] = *(const float4*)(src + CDIM + c4);
      *(float4*)&Vs[r][c4] = *(const float4*)(src + 2 * CDIM + c4);
    }
    __syncthreads();
    for (int j = 0; j < 128; ++j) {
      const float4* kp = (const float4*)&Ks[j][0];
      float s = 0.f;
#pragma unroll
      for (int i4 = 0; i4 < 16; ++i4) {
        float4 kv4 = kp[i4];
        s += q[i4 * 4 + 0] * kv4.x + q[i4 * 4 + 1] * kv4.y +
             q[i4 * 4 + 2] * kv4.z + q[i4 * 4 + 3] * kv4.w;
      }
      s *= 0.125f;
      const float4* vp = (const float4*)&Vs[j][0];
      if (s <= mrun) {
        float pe = __expf(s - mrun);
        lrun += pe;
#pragma unroll
        for (int i4 = 0; i4 < 16; ++i4) {
          float4 vv = vp[i4];
          o[i4 * 4 + 0] += pe * vv.x; o[i4 * 4 + 1] += pe * vv.y;
          o[i4 * 4 + 2] += pe * vv.z; o[i4 * 4 + 3] += pe * vv.w;
        }
      } else {
        float corr = __expf(mrun - s);
        mrun = s;
        lrun = lrun * corr + 1.f;
#pragma unroll
        for (int i4 = 0; i4 < 16; ++i4) {
          float4 vv = vp[i4];
          o[i4 * 4 + 0] = o[i4 * 4 + 0] * corr + vv.x;
          o[i4 * 4 + 1] = o[i4 * 4 + 1] * corr + vv.y;
          o[i4 * 4 + 2] = o[i4 * 4 + 2] * corr + vv.z;
          o[i4 * 4 + 3] = o[i4 * 4 + 3] * corr + vv.w;
        }
      }
    }
  }
  float inv = 1.f / lrun;
  unsigned short* op = o_buf + ((size_t)(b * LSEQ + p)) * CDIM + h * HD;
#pragma unroll
  for (int i = 0; i < 16; ++i) {
    ushort4 u;
    u.x = f2bf(o[i * 4 + 0] * inv); u.y = f2bf(o[i * 4 + 1] * inv);
    u.z = f2bf(o[i * 4 + 2] * inv); u.w = f2bf(o[i * 4 + 3] * inv);
    *(ushort4*)(op + i * 4) = u;
  }
}

// ---------------------------------------------------------------------------
// Cross-attn scores + streaming top-16 (fp32, stable ties).
// ---------------------------------------------------------------------------
__global__ __launch_bounds__(256)
void k_cross_topk(const float* __restrict__ qb, const float* __restrict__ kvb,
                  float* __restrict__ topS, int* __restrict__ topI) {
  __shared__ float Ks[128][HD];
  int qc = blockIdx.x, h = blockIdx.y, b = blockIdx.z;
  int t = threadIdx.x;

  int qrow = qc * 256 + t;
  const float* qp = qb + ((size_t)(b * LSEQ + qrow)) * CDIM + h * HD;
  float q[HD];
#pragma unroll
  for (int i = 0; i < 16; ++i) *(float4*)&q[i * 4] = *(const float4*)(qp + i * 4);

  float s16[TK];
  int i16[TK];
#pragma unroll
  for (int i = 0; i < TK; ++i) { s16[i] = -1e30f; i16[i] = 0; }
  float smin = -1e30f;

  for (int kc = 0; kc < 8; ++kc) {
    __syncthreads();
#pragma unroll
    for (int i = 0; i < 8; ++i) {
      int f = t + i * 256;
      int r = f >> 4, c4 = (f & 15) * 4;
      *(float4*)&Ks[r][c4] =
          *(const float4*)(kvb + ((size_t)(b * LCTX + kc * 128 + r)) * 2048 + h * HD + c4);
    }
    __syncthreads();
    for (int j = 0; j < 128; ++j) {
      const float4* kp = (const float4*)&Ks[j][0];
      float s = 0.f;
#pragma unroll
      for (int i4 = 0; i4 < 16; ++i4) {
        float4 kv4 = kp[i4];
        s += q[i4 * 4 + 0] * kv4.x + q[i4 * 4 + 1] * kv4.y +
             q[i4 * 4 + 2] * kv4.z + q[i4 * 4 + 3] * kv4.w;
      }
      s *= 0.125f;
      if (s > smin) {
        int kidx = kc * 128 + j;
#pragma unroll
        for (int i = TK - 1; i >= 1; --i) {
          float up = s16[i - 1];
          if (up < s) { s16[i] = up; i16[i] = i16[i - 1]; }
          else if (s16[i] < s) { s16[i] = s; i16[i] = kidx; }
        }
        if (s16[0] < s) { s16[0] = s; i16[0] = kidx; }
        smin = s16[TK - 1];
      }
    }
  }
  size_t rbase = ((size_t)((b * HN + h) * LSEQ + qrow)) * TK;
#pragma unroll
  for (int i = 0; i < TK; ++i) { topS[rbase + i] = s16[i]; topI[rbase + i] = i16[i]; }
}

// ---------------------------------------------------------------------------
// Softmax over top-16 + V gather -> bf16. One wave per (b,h,q) row; lane = d.
// ---------------------------------------------------------------------------
__global__ __launch_bounds__(256)
void k_cross_gather(const float* __restrict__ topS, const int* __restrict__ topI,
                    const float* __restrict__ kvb, unsigned short* __restrict__ o2) {
  int t = threadIdx.x;
  int wid = t >> 6, lane = t & 63;
  int r = blockIdx.x * 4 + wid;
  int b = r >> 16;
  int h = (r >> 12) & 15;
  int q = r & 4095;
  const float* sp = topS + (size_t)r * TK;
  const int* ip = topI + (size_t)r * TK;
  float sv[TK], pv[TK];
  int iv[TK];
#pragma unroll
  for (int i = 0; i < TK; ++i) { sv[i] = sp[i]; iv[i] = ip[i]; }
  float mx = sv[0];
  float sum = 0.f;
#pragma unroll
  for (int i = 0; i < TK; ++i) { pv[i] = __expf(sv[i] - mx); sum += pv[i]; }
  float inv = 1.f / sum;
  float acc = 0.f;
#pragma unroll
  for (int i = 0; i < TK; ++i)
    acc += pv[i] * kvb[((size_t)(b * LCTX + iv[i])) * 2048 + CDIM + h * HD + lane];
  o2[((size_t)(b * LSEQ + q)) * CDIM + h * HD + lane] = f2bf(acc * inv);
}

// ---------------------------------------------------------------------------
// g = silu(u[:, :HID]) * u[:, HID:]  -> bf16
// ---------------------------------------------------------------------------
__global__ __launch_bounds__(256)
void k_silu_mul(const float* __restrict__ U, unsigned short* __restrict__ G, int rows) {
  int id = blockIdx.x * 256 + threadIdx.x;
  int total = rows * (HIDDIM / 4);
  if (id >= total) return;
  int row = id >> 10;
  int c4 = id & 1023;
  const float4* ua = (const float4*)U + (size_t)row * (2 * HIDDIM / 4) + c4;
  float4 a = *ua;
  float4 bb = *(ua + HIDDIM / 4);
  ushort4 u;
  u.x = f2bf(a.x / (1.f + __expf(-a.x)) * bb.x);
  u.y = f2bf(a.y / (1.f + __expf(-a.y)) * bb.y);
  u.z = f2bf(a.z / (1.f + __expf(-a.z)) * bb.z);
  u.w = f2bf(a.w / (1.f + __expf(-a.w)) * bb.w);
  ((ushort4*)G)[(size_t)row * (HIDDIM / 4) + c4] = u;
}

// ---------------------------------------------------------------------------
extern "C" void kernel_launch(void* const* d_in, const int* in_sizes, int n_in,
                              void* d_out, int out_size, void* d_ws, size_t ws_size,
                              hipStream_t stream) {
  const float* x0    = (const float*)d_in[0];
  const float* mod   = (const float*)d_in[1];
  const float* ctx   = (const float*)d_in[2];
  const float* w_ada = (const float*)d_in[3];
  const float* b_ada = (const float*)d_in[4];
  const float* w_qkv = (const float*)d_in[5];
  const float* b_qkv = (const float*)d_in[6];
  const float* w_so  = (const float*)d_in[7];
  const float* b_so  = (const float*)d_in[8];
  const float* w_q   = (const float*)d_in[9];
  const float* b_q   = (const float*)d_in[10];
  const float* w_kv  = (const float*)d_in[11];
  const float* b_kv  = (const float*)d_in[12];
  const float* w_co  = (const float*)d_in[13];
  const float* b_co  = (const float*)d_in[14];
  const float* w_m1  = (const float*)d_in[15];
  const float* b_m1  = (const float*)d_in[16];
  const float* w_m2  = (const float*)d_in[17];
  const float* b_m2  = (const float*)d_in[18];
  float* out = (float*)d_out;

  char* p = (char*)d_ws;
  float* mb = (float*)p;                 p += 18432 * 4;
  unsigned short* ctxb = (unsigned short*)p;   p += (size_t)2048 * 1024 * 2;
  unsigned short* wtqkv = (unsigned short*)p;  p += (size_t)3072 * 1024 * 2;
  unsigned short* wtso = (unsigned short*)p;   p += (size_t)1024 * 1024 * 2;
  unsigned short* wtq = (unsigned short*)p;    p += (size_t)1024 * 1024 * 2;
  unsigned short* wtkv = (unsigned short*)p;   p += (size_t)2048 * 1024 * 2;
  unsigned short* wtco = (unsigned short*)p;   p += (size_t)1024 * 1024 * 2;
  unsigned short* wtm1 = (unsigned short*)p;   p += (size_t)8192 * 1024 * 2;
  unsigned short* wtm2 = (unsigned short*)p;   p += (size_t)1024 * 4096 * 2;
  unsigned short* hb = (unsigned short*)p;     p += (size_t)8192 * 1024 * 2;
  float* xb = (float*)p;                 p += (size_t)8192 * 1024 * 4;
  char* R1 = p;                          p += (size_t)8192 * 3072 * 4;
  unsigned short* o_bf = (unsigned short*)p;   p += (size_t)8192 * 1024 * 2;
  float* qf = (float*)p;                 p += (size_t)8192 * 1024 * 4;
  // R1 time-multiplexed:
  float* qkvf = (float*)R1;                          // steps 4-5
  float* kvf = (float*)R1;                           // steps 9-11
  float* Ubuf = (float*)R1;                          // step 13 (per chunk)
  unsigned short* Gbuf = (unsigned short*)(R1 + (size_t)2048 * 8192 * 4);
  float* topS = (float*)(R1 + (size_t)2048 * 8192 * 4 + (size_t)2048 * 4096 * 2);
  int* topI = (int*)(topS + (size_t)131072 * TK);

  // 1. modulation
  k_mod_ada<<<dim3(36, 2), 256, 0, stream>>>(mod, w_ada, b_ada, mb);
  // 2. weight transposes + ctx cast
  k_wt<<<dim3(96, 32), 256, 0, stream>>>(w_qkv, wtqkv, 1024, 3072);
  k_wt<<<dim3(32, 32), 256, 0, stream>>>(w_so, wtso, 1024, 1024);
  k_wt<<<dim3(32, 32), 256, 0, stream>>>(w_q, wtq, 1024, 1024);
  k_wt<<<dim3(64, 32), 256, 0, stream>>>(w_kv, wtkv, 1024, 2048);
  k_wt<<<dim3(32, 32), 256, 0, stream>>>(w_co, wtco, 1024, 1024);
  k_wt<<<dim3(256, 32), 256, 0, stream>>>(w_m1, wtm1, 1024, 8192);
  k_wt<<<dim3(32, 128), 256, 0, stream>>>(w_m2, wtm2, 4096, 1024);
  k_cast_bf<<<2048, 256, 0, stream>>>(ctx, ctxb, 524288);
  // 3. LN1
  k_ln_mod<<<8192, 256, 0, stream>>>(x0, mb, hb, 0, 1);
  // 4. qkv projection
  k_gemm_bf<0><<<dim3(24, 64), 256, 0, stream>>>(hb, wtqkv, b_qkv, qkvf,
                                                 nullptr, nullptr, 8192, 3072, 1024, 0, 0);
  // 5. self-attention
  k_self_attn<<<256, 512, 0, stream>>>(qkvf, o_bf);
  // 6. so proj + residual
  k_gemm_bf<1><<<dim3(8, 64), 256, 0, stream>>>(o_bf, wtso, b_so, xb,
                                                x0, mb, 8192, 1024, 1024, 2, 0);
  // 7. LN2
  k_ln_mod<<<8192, 256, 0, stream>>>(xb, mb, hb, 3, 4);
  // 8. q projection
  k_gemm_bf<0><<<dim3(8, 64), 256, 0, stream>>>(hb, wtq, b_q, qf,
                                                nullptr, nullptr, 8192, 1024, 1024, 0, 0);
  // 9. kv projection
  k_gemm_bf<0><<<dim3(16, 16), 256, 0, stream>>>(ctxb, wtkv, b_kv, kvf,
                                                 nullptr, nullptr, 2048, 2048, 1024, 0, 0);
  // 10. cross topk
  k_cross_topk<<<dim3(16, 16, 2), 256, 0, stream>>>(qf, kvf, topS, topI);
  // 11. gather
  k_cross_gather<<<32768, 256, 0, stream>>>(topS, topI, kvf, o_bf);
  // 12. co proj + residual (in-place xb)
  k_gemm_bf<1><<<dim3(8, 64), 256, 0, stream>>>(o_bf, wtco, b_co, xb,
                                                xb, mb, 8192, 1024, 1024, 5, 0);
  // 13. LN3
  k_ln_mod<<<8192, 256, 0, stream>>>(xb, mb, hb, 6, 7);
  // 14. swiglu chunks
  for (int ch = 0; ch < 4; ++ch) {
    const unsigned short* hA = hb + (size_t)ch * 2048 * 1024;
    k_gemm_bf<0><<<dim3(64, 16), 256, 0, stream>>>(hA, wtm1, b_m1, Ubuf,
                                                   nullptr, nullptr, 2048, 8192, 1024, 0, 0);
    k_silu_mul<<<8192, 256, 0, stream>>>(Ubuf, Gbuf, 2048);
    k_gemm_bf<1><<<dim3(8, 16), 256, 0, stream>>>(Gbuf, wtm2, b_m2,
                                                  out + (size_t)ch * 2048 * 1024,
                                                  xb + (size_t)ch * 2048 * 1024, mb,
                                                  2048, 1024, 4096, 8, ch * 2048);
  }
}

// Round 4
// 2031.133 us; speedup vs baseline: 3.9894x; 1.2888x over previous
//
#include <hip/hip_runtime.h>
#include <cstdint>
#include <cstddef>

#define CDIM 1024
#define HN 16
#define HD 64
#define WINSZ 512
#define SHIFTSZ 256
#define TK 16
#define HIDDIM 4096
#define LSEQ 4096
#define NCOL9 9216
#define LCTX 1024

typedef __bf16 bf16x8 __attribute__((ext_vector_type(8)));
typedef float f32x4 __attribute__((ext_vector_type(4)));

static __device__ __forceinline__ unsigned short f2bf(float f) {
  unsigned u = __float_as_uint(f);
  unsigned r = (u + 0x7fffu + ((u >> 16) & 1u)) >> 16;
  return (unsigned short)r;
}

// ---------------------------------------------------------------------------
// m = silu(mod) @ w_ada + b_ada      (2 x 9216)
// ---------------------------------------------------------------------------
__global__ __launch_bounds__(256)
void k_mod_ada(const float* __restrict__ mod, const float* __restrict__ w_ada,
               const float* __restrict__ b_ada, float* __restrict__ m_out) {
  __shared__ float sm[CDIM];
  int b = blockIdx.y;
  int t = threadIdx.x;
  for (int k = t; k < CDIM; k += 256) {
    float v = mod[b * CDIM + k];
    sm[k] = v / (1.f + __expf(-v));
  }
  __syncthreads();
  int j = blockIdx.x * 256 + t;
  float acc = b_ada[j];
#pragma unroll 8
  for (int k = 0; k < CDIM; ++k) acc += sm[k] * w_ada[(size_t)k * NCOL9 + j];
  m_out[b * NCOL9 + j] = acc;
}

// ---------------------------------------------------------------------------
// Weight transpose + cast: W[K][N] fp32 -> WT[N][K] bf16 bits
// ---------------------------------------------------------------------------
__global__ __launch_bounds__(256)
void k_wt(const float* __restrict__ W, unsigned short* __restrict__ WT,
          int K, int N) {
  __shared__ float tl[32][33];
  int tx = threadIdx.x & 31, ty = threadIdx.x >> 5;
  int n0 = blockIdx.x * 32, k0 = blockIdx.y * 32;
#pragma unroll
  for (int i = 0; i < 4; ++i)
    tl[ty + i * 8][tx] = W[(size_t)(k0 + ty + i * 8) * N + n0 + tx];
  __syncthreads();
#pragma unroll
  for (int i = 0; i < 4; ++i) {
    int n = ty + i * 8;
    WT[(size_t)(n0 + n) * K + k0 + tx] = f2bf(tl[tx][n]);
  }
}

// fp32 -> bf16 elementwise
__global__ __launch_bounds__(256)
void k_cast_bf(const float* __restrict__ in, unsigned short* __restrict__ o, int n4) {
  int id = blockIdx.x * 256 + threadIdx.x;
  if (id >= n4) return;
  float4 v = ((const float4*)in)[id];
  ushort4 u;
  u.x = f2bf(v.x); u.y = f2bf(v.y); u.z = f2bf(v.z); u.w = f2bf(v.w);
  ((ushort4*)o)[id] = u;
}

// ---------------------------------------------------------------------------
// h = ln(x) * (1 + sc) + sh  -> bf16   (one block per row)
// ---------------------------------------------------------------------------
__global__ __launch_bounds__(256)
void k_ln_mod(const float* __restrict__ x, const float* __restrict__ mbuf,
              unsigned short* __restrict__ h, int shsel, int scsel) {
  __shared__ float ws1[4], ws2[4], sstat[2];
  int row = blockIdx.x;
  int b = row >> 12;
  int t = threadIdx.x;
  const float4* xr = (const float4*)(x + (size_t)row * CDIM);
  float4 v = xr[t];
  float s1 = v.x + v.y + v.z + v.w;
  float s2 = v.x * v.x + v.y * v.y + v.z * v.z + v.w * v.w;
  for (int off = 32; off; off >>= 1) {
    s1 += __shfl_down(s1, off);
    s2 += __shfl_down(s2, off);
  }
  int wid = t >> 6, lane = t & 63;
  if (lane == 0) { ws1[wid] = s1; ws2[wid] = s2; }
  __syncthreads();
  if (t == 0) {
    float a = 0.f, c = 0.f;
    for (int i = 0; i < 4; ++i) { a += ws1[i]; c += ws2[i]; }
    float mean = a * (1.f / CDIM);
    float var = c * (1.f / CDIM) - mean * mean;
    sstat[0] = mean;
    sstat[1] = rsqrtf(var + 1e-6f);
  }
  __syncthreads();
  float mean = sstat[0], rstd = sstat[1];
  const float* sc = mbuf + b * NCOL9 + scsel * CDIM;
  const float* sh = mbuf + b * NCOL9 + shsel * CDIM;
  int c0 = t * 4;
  ushort4 u;
  u.x = f2bf((v.x - mean) * rstd * (1.f + sc[c0 + 0]) + sh[c0 + 0]);
  u.y = f2bf((v.y - mean) * rstd * (1.f + sc[c0 + 1]) + sh[c0 + 1]);
  u.z = f2bf((v.z - mean) * rstd * (1.f + sc[c0 + 2]) + sh[c0 + 2]);
  u.w = f2bf((v.w - mean) * rstd * (1.f + sc[c0 + 3]) + sh[c0 + 3]);
  *(ushort4*)(h + (size_t)row * CDIM + c0) = u;
}

// ---------------------------------------------------------------------------
// bf16 MFMA GEMM: out[M][N] = Abf[M][K] @ WT[N][K]^T + bias
// EPI=1: out = xres + (acc + bias) * g[b, n]   (fp32 out)
// OUTBF=1: bf16 output (no EPI)
// ---------------------------------------------------------------------------
template <int EPI, int OUTBF>
__global__ __launch_bounds__(256)
void k_gemm_bf(const unsigned short* __restrict__ Ab,
               const unsigned short* __restrict__ Bt,
               const float* __restrict__ bias, void* __restrict__ outp,
               const float* __restrict__ xres, const float* __restrict__ mbuf,
               int M, int N, int K, int gsel, int row0) {
  __shared__ unsigned short lsA[128 * 32];
  __shared__ unsigned short lsB[128 * 32];
  int t = threadIdx.x;
  int bm = blockIdx.y, bn = blockIdx.x;
  int l = t & 63, wv = t >> 6;
  int wm = wv >> 1, wn = wv & 1;
  int lane15 = l & 15, hw = l >> 4;

  int d0 = t, d1 = t + 256;
  int r0 = d0 >> 2, sl0 = (d0 & 3) ^ ((d0 >> 3) & 3);
  int r1 = d1 >> 2, sl1 = (d1 & 3) ^ ((d1 >> 3) & 3);
  const unsigned short* a_src0 = Ab + (size_t)(bm * 128 + r0) * K + sl0 * 8;
  const unsigned short* a_src1 = Ab + (size_t)(bm * 128 + r1) * K + sl1 * 8;
  const unsigned short* b_src0 = Bt + (size_t)(bn * 128 + r0) * K + sl0 * 8;
  const unsigned short* b_src1 = Bt + (size_t)(bn * 128 + r1) * K + sl1 * 8;

  f32x4 acc[4][4];
#pragma unroll
  for (int i = 0; i < 4; ++i)
#pragma unroll
    for (int j = 0; j < 4; ++j) acc[i][j] = (f32x4){0.f, 0.f, 0.f, 0.f};

  auto stage = [&](int kt) {
    int ko = kt * 32;
    __builtin_amdgcn_global_load_lds(
        (const __attribute__((address_space(1))) void*)(a_src0 + ko),
        (__attribute__((address_space(3))) void*)(lsA + d0 * 8), 16, 0, 0);
    __builtin_amdgcn_global_load_lds(
        (const __attribute__((address_space(1))) void*)(a_src1 + ko),
        (__attribute__((address_space(3))) void*)(lsA + d1 * 8), 16, 0, 0);
    __builtin_amdgcn_global_load_lds(
        (const __attribute__((address_space(1))) void*)(b_src0 + ko),
        (__attribute__((address_space(3))) void*)(lsB + d0 * 8), 16, 0, 0);
    __builtin_amdgcn_global_load_lds(
        (const __attribute__((address_space(1))) void*)(b_src1 + ko),
        (__attribute__((address_space(3))) void*)(lsB + d1 * 8), 16, 0, 0);
  };

  stage(0);

  int swz = ((lane15 >> 1) & 3) << 4;
  int aoff = (wm * 64 + lane15) * 64 + (((hw << 4) ^ swz));
  int boff = (wn * 64 + lane15) * 64 + (((hw << 4) ^ swz));

  int nk = K >> 5;
  for (int kt = 0; kt < nk; ++kt) {
    __syncthreads();
    bf16x8 af[4], bfr[4];
#pragma unroll
    for (int i = 0; i < 4; ++i) {
      af[i]  = *reinterpret_cast<const bf16x8*>((const char*)lsA + aoff + i * 1024);
      bfr[i] = *reinterpret_cast<const bf16x8*>((const char*)lsB + boff + i * 1024);
    }
#pragma unroll
    for (int mi = 0; mi < 4; ++mi)
#pragma unroll
      for (int ni = 0; ni < 4; ++ni)
        acc[mi][ni] = __builtin_amdgcn_mfma_f32_16x16x32_bf16(
            af[mi], bfr[ni], acc[mi][ni], 0, 0, 0);
    __syncthreads();
    if (kt + 1 < nk) stage(kt + 1);
  }

  const float* g = nullptr;
  if (EPI) g = mbuf + ((size_t)((row0 + bm * 128) >> 12)) * NCOL9 + gsel * CDIM;
#pragma unroll
  for (int ni = 0; ni < 4; ++ni) {
    int gcol = bn * 128 + wn * 64 + ni * 16 + lane15;
    float bs = bias[gcol];
    float gg = EPI ? g[gcol] : 0.f;
#pragma unroll
    for (int mi = 0; mi < 4; ++mi) {
      int grow0 = bm * 128 + wm * 64 + mi * 16 + hw * 4;
      f32x4 v = acc[mi][ni];
#pragma unroll
      for (int rr = 0; rr < 4; ++rr) {
        size_t idx = (size_t)(grow0 + rr) * N + gcol;
        float ov = v[rr] + bs;
        if (EPI) ov = xres[idx] + ov * gg;
        if (OUTBF) ((unsigned short*)outp)[idx] = f2bf(ov);
        else ((float*)outp)[idx] = ov;
      }
    }
  }
}

// ---------------------------------------------------------------------------
// Windowed shifted self-attention (fp32 math, bf16 output).
// ---------------------------------------------------------------------------
__global__ __launch_bounds__(512, 1)
void k_self_attn(const float* __restrict__ qkv, unsigned short* __restrict__ o_buf) {
  __shared__ float Ks[128][HD];
  __shared__ float Vs[128][HD];
  int blk = blockIdx.x;
  int b = blk >> 7;
  int w = (blk >> 4) & 7;
  int h = blk & 15;
  int t = threadIdx.x;

  int p = (w * WINSZ + t + SHIFTSZ) & (LSEQ - 1);
  const float* qrow = qkv + ((size_t)(b * LSEQ + p)) * 3072 + h * HD;
  float q[HD];
#pragma unroll
  for (int i = 0; i < 16; ++i) *(float4*)&q[i * 4] = *(const float4*)(qrow + i * 4);

  float o[HD];
#pragma unroll
  for (int d = 0; d < HD; ++d) o[d] = 0.f;
  float mrun = -1e30f, lrun = 0.f;

  for (int kc = 0; kc < 4; ++kc) {
    __syncthreads();
#pragma unroll
    for (int i = 0; i < 4; ++i) {
      int f = t + i * 512;
      int r = f >> 4, c4 = (f & 15) * 4;
      int pk = (w * WINSZ + kc * 128 + r + SHIFTSZ) & (LSEQ - 1);
      const float* src = qkv + ((size_t)(b * LSEQ + pk)) * 3072 + h * HD;
      *(float4*)&Ks[r][c4] = *(const float4*)(src + CDIM + c4);
      *(float4*)&Vs[r][c4] = *(const float4*)(src + 2 * CDIM + c4);
    }
    __syncthreads();
    for (int j = 0; j < 128; ++j) {
      const float4* kp = (const float4*)&Ks[j][0];
      float s = 0.f;
#pragma unroll
      for (int i4 = 0; i4 < 16; ++i4) {
        float4 kv4 = kp[i4];
        s += q[i4 * 4 + 0] * kv4.x + q[i4 * 4 + 1] * kv4.y +
             q[i4 * 4 + 2] * kv4.z + q[i4 * 4 + 3] * kv4.w;
      }
      s *= 0.125f;
      const float4* vp = (const float4*)&Vs[j][0];
      if (s <= mrun) {
        float pe = __expf(s - mrun);
        lrun += pe;
#pragma unroll
        for (int i4 = 0; i4 < 16; ++i4) {
          float4 vv = vp[i4];
          o[i4 * 4 + 0] += pe * vv.x; o[i4 * 4 + 1] += pe * vv.y;
          o[i4 * 4 + 2] += pe * vv.z; o[i4 * 4 + 3] += pe * vv.w;
        }
      } else {
        float corr = __expf(mrun - s);
        mrun = s;
        lrun = lrun * corr + 1.f;
#pragma unroll
        for (int i4 = 0; i4 < 16; ++i4) {
          float4 vv = vp[i4];
          o[i4 * 4 + 0] = o[i4 * 4 + 0] * corr + vv.x;
          o[i4 * 4 + 1] = o[i4 * 4 + 1] * corr + vv.y;
          o[i4 * 4 + 2] = o[i4 * 4 + 2] * corr + vv.z;
          o[i4 * 4 + 3] = o[i4 * 4 + 3] * corr + vv.w;
        }
      }
    }
  }
  float inv = 1.f / lrun;
  unsigned short* op = o_buf + ((size_t)(b * LSEQ + p)) * CDIM + h * HD;
#pragma unroll
  for (int i = 0; i < 16; ++i) {
    ushort4 u;
    u.x = f2bf(o[i * 4 + 0] * inv); u.y = f2bf(o[i * 4 + 1] * inv);
    u.z = f2bf(o[i * 4 + 2] * inv); u.w = f2bf(o[i * 4 + 3] * inv);
    *(ushort4*)(op + i * 4) = u;
  }
}

// ---------------------------------------------------------------------------
// Cross-attn scores via MFMA, packed epilogue:
// packed = (monotonic_key(s) & 0xFFFFFC00) | (1023 - k)   -> Sp[b][h][ql][k]
// Grid: (ktile=8, qtile=4, bh=32), block 256, q-chunk of 512 rows.
// ---------------------------------------------------------------------------
__global__ __launch_bounds__(256)
void k_cross_scores(const unsigned short* __restrict__ qb,
                    const unsigned short* __restrict__ kvb,
                    unsigned* __restrict__ Sp, int q0) {
  __shared__ unsigned short lsA[128 * 64];
  __shared__ unsigned short lsB[128 * 64];
  int t = threadIdx.x;
  int kt = blockIdx.x, qt = blockIdx.y, bh = blockIdx.z;
  int b = bh >> 4, h = bh & 15;
  int l = t & 63, wv = t >> 6;
  int wm = wv >> 1, wn = wv & 1;
  int lane15 = l & 15, hw = l >> 4;

  const unsigned short* Abase = qb + ((size_t)(b * LSEQ + q0 + qt * 128)) * CDIM + h * HD;
  const unsigned short* Bbase = kvb + ((size_t)(b * LCTX + kt * 128)) * 2048 + h * HD;

  // stage A,B: rows of 128B (8x16B chunks), slot pre-swizzled by row&7
#pragma unroll
  for (int i = 0; i < 4; ++i) {
    int c = t + i * 256;
    int r = c >> 3, sl = c & 7;
    int gsl = sl ^ (r & 7);
    __builtin_amdgcn_global_load_lds(
        (const __attribute__((address_space(1))) void*)(Abase + (size_t)r * CDIM + gsl * 8),
        (__attribute__((address_space(3))) void*)(lsA + c * 8), 16, 0, 0);
    __builtin_amdgcn_global_load_lds(
        (const __attribute__((address_space(1))) void*)(Bbase + (size_t)r * 2048 + gsl * 8),
        (__attribute__((address_space(3))) void*)(lsB + c * 8), 16, 0, 0);
  }
  __syncthreads();

  f32x4 acc[4][4];
#pragma unroll
  for (int i = 0; i < 4; ++i)
#pragma unroll
    for (int j = 0; j < 4; ++j) acc[i][j] = (f32x4){0.f, 0.f, 0.f, 0.f};

#pragma unroll
  for (int ks = 0; ks < 2; ++ks) {
    bf16x8 af[4], bfr[4];
#pragma unroll
    for (int i = 0; i < 4; ++i) {
      int ar = wm * 64 + i * 16 + lane15;
      int br = wn * 64 + i * 16 + lane15;
      int sa = (ks * 4 + hw) ^ (ar & 7);
      int sb = (ks * 4 + hw) ^ (br & 7);
      af[i]  = *reinterpret_cast<const bf16x8*>((const char*)lsA + ar * 128 + sa * 16);
      bfr[i] = *reinterpret_cast<const bf16x8*>((const char*)lsB + br * 128 + sb * 16);
    }
#pragma unroll
    for (int mi = 0; mi < 4; ++mi)
#pragma unroll
      for (int ni = 0; ni < 4; ++ni)
        acc[mi][ni] = __builtin_amdgcn_mfma_f32_16x16x32_bf16(
            af[mi], bfr[ni], acc[mi][ni], 0, 0, 0);
  }

  size_t obase = (size_t)(bh * 512) * 1024;
#pragma unroll
  for (int ni = 0; ni < 4; ++ni) {
    int kcol = kt * 128 + wn * 64 + ni * 16 + lane15;
#pragma unroll
    for (int mi = 0; mi < 4; ++mi) {
      int qr0 = qt * 128 + wm * 64 + mi * 16 + hw * 4;
#pragma unroll
      for (int rr = 0; rr < 4; ++rr) {
        float s = acc[mi][ni][rr] * 0.125f;
        unsigned u = __float_as_uint(s);
        unsigned key = ((int)u >= 0) ? (u | 0x80000000u) : ~u;
        unsigned pk = (key & 0xFFFFFC00u) | (unsigned)(1023 - kcol);
        Sp[obase + (size_t)(qr0 + rr) * 1024 + kcol] = pk;
      }
    }
  }
}

// ---------------------------------------------------------------------------
// Wave-per-row top-16 (bitonic, packed u32) + softmax + V gather -> bf16.
// ---------------------------------------------------------------------------
__global__ __launch_bounds__(256)
void k_topk_gather(const unsigned* __restrict__ Sp, const float* __restrict__ kvf,
                   unsigned short* __restrict__ o2, int q0) {
  int t = threadIdx.x;
  int lane = t & 63;
  int lr = blockIdx.x * 4 + (t >> 6);   // [0, 16384): b(2) x h(16) x ql(512)
  int b = lr >> 13;
  int h = (lr >> 9) & 15;
  int ql = lr & 511;

  const uint4* sp = (const uint4*)(Sp + (size_t)lr * 1024);
  unsigned v[16];
#pragma unroll
  for (int r = 0; r < 4; ++r) {
    uint4 x = sp[lane + r * 64];
    v[r * 4 + 0] = x.x; v[r * 4 + 1] = x.y; v[r * 4 + 2] = x.z; v[r * 4 + 3] = x.w;
  }

  // bitonic sort 16 desc (CE = max/min on packed u32)
#pragma unroll
  for (int k = 2; k <= 16; k <<= 1) {
#pragma unroll
    for (int j = k >> 1; j > 0; j >>= 1) {
#pragma unroll
      for (int i = 0; i < 16; ++i) {
        int lidx = i ^ j;
        if (lidx > i) {
          unsigned a = v[i], c = v[lidx];
          unsigned hi = a > c ? a : c, lo = a > c ? c : a;
          if ((i & k) == 0) { v[i] = hi; v[lidx] = lo; }
          else { v[i] = lo; v[lidx] = hi; }
        }
      }
    }
  }

  // 6 xor-merge rounds: keep top-16 of (mine, partner)
#pragma unroll
  for (int st = 0; st < 6; ++st) {
    unsigned pv[16];
#pragma unroll
    for (int i = 0; i < 16; ++i)
      pv[i] = (unsigned)__shfl_xor((int)v[i], 1 << st);
#pragma unroll
    for (int i = 0; i < 16; ++i) {
      unsigned c = pv[15 - i];
      v[i] = v[i] > c ? v[i] : c;
    }
    // clean bitonic -> descending
#pragma unroll
    for (int j = 8; j > 0; j >>= 1) {
#pragma unroll
      for (int i = 0; i < 16; ++i) {
        if ((i & j) == 0) {
          int lidx = i | j;
          unsigned a = v[i], c = v[lidx];
          v[i] = a > c ? a : c;
          v[lidx] = a > c ? c : a;
        }
      }
    }
  }

  // unpack, softmax, gather
  float sv[16];
  int iv[16];
#pragma unroll
  for (int i = 0; i < 16; ++i) {
    unsigned pk = v[i];
    unsigned key = pk & 0xFFFFFC00u;
    unsigned ub = (key & 0x80000000u) ? (key & 0x7FFFFFFFu) : ~key;
    sv[i] = __uint_as_float(ub);
    iv[i] = 1023 - (int)(pk & 1023u);
  }
  float mx = sv[0];
#pragma unroll
  for (int i = 1; i < 16; ++i) mx = fmaxf(mx, sv[i]);
  float pw[16], sum = 0.f;
#pragma unroll
  for (int i = 0; i < 16; ++i) { pw[i] = __expf(sv[i] - mx); sum += pw[i]; }
  float inv = 1.f / sum;

  const float* vb = kvf + ((size_t)b * LCTX) * 2048 + CDIM + h * HD + lane;
  float o = 0.f;
#pragma unroll
  for (int i = 0; i < 16; ++i) o += pw[i] * vb[(size_t)iv[i] * 2048];

  int q = q0 + ql;
  o2[((size_t)(b * LSEQ + q)) * CDIM + h * HD + lane] = f2bf(o * inv);
}

// ---------------------------------------------------------------------------
// g = silu(u[:, :HID]) * u[:, HID:]  -> bf16
// ---------------------------------------------------------------------------
__global__ __launch_bounds__(256)
void k_silu_mul(const float* __restrict__ U, unsigned short* __restrict__ G, int rows) {
  int id = blockIdx.x * 256 + threadIdx.x;
  int total = rows * (HIDDIM / 4);
  if (id >= total) return;
  int row = id >> 10;
  int c4 = id & 1023;
  const float4* ua = (const float4*)U + (size_t)row * (2 * HIDDIM / 4) + c4;
  float4 a = *ua;
  float4 bb = *(ua + HIDDIM / 4);
  ushort4 u;
  u.x = f2bf(a.x / (1.f + __expf(-a.x)) * bb.x);
  u.y = f2bf(a.y / (1.f + __expf(-a.y)) * bb.y);
  u.z = f2bf(a.z / (1.f + __expf(-a.z)) * bb.z);
  u.w = f2bf(a.w / (1.f + __expf(-a.w)) * bb.w);
  ((ushort4*)G)[(size_t)row * (HIDDIM / 4) + c4] = u;
}

// ---------------------------------------------------------------------------
extern "C" void kernel_launch(void* const* d_in, const int* in_sizes, int n_in,
                              void* d_out, int out_size, void* d_ws, size_t ws_size,
                              hipStream_t stream) {
  const float* x0    = (const float*)d_in[0];
  const float* mod   = (const float*)d_in[1];
  const float* ctx   = (const float*)d_in[2];
  const float* w_ada = (const float*)d_in[3];
  const float* b_ada = (const float*)d_in[4];
  const float* w_qkv = (const float*)d_in[5];
  const float* b_qkv = (const float*)d_in[6];
  const float* w_so  = (const float*)d_in[7];
  const float* b_so  = (const float*)d_in[8];
  const float* w_q   = (const float*)d_in[9];
  const float* b_q   = (const float*)d_in[10];
  const float* w_kv  = (const float*)d_in[11];
  const float* b_kv  = (const float*)d_in[12];
  const float* w_co  = (const float*)d_in[13];
  const float* b_co  = (const float*)d_in[14];
  const float* w_m1  = (const float*)d_in[15];
  const float* b_m1  = (const float*)d_in[16];
  const float* w_m2  = (const float*)d_in[17];
  const float* b_m2  = (const float*)d_in[18];
  float* out = (float*)d_out;

  char* p = (char*)d_ws;
  float* mb = (float*)p;                 p += 18432 * 4;
  unsigned short* ctxb = (unsigned short*)p;   p += (size_t)2048 * 1024 * 2;
  unsigned short* wtqkv = (unsigned short*)p;  p += (size_t)3072 * 1024 * 2;
  unsigned short* wtso = (unsigned short*)p;   p += (size_t)1024 * 1024 * 2;
  unsigned short* wtq = (unsigned short*)p;    p += (size_t)1024 * 1024 * 2;
  unsigned short* wtkv = (unsigned short*)p;   p += (size_t)2048 * 1024 * 2;
  unsigned short* wtco = (unsigned short*)p;   p += (size_t)1024 * 1024 * 2;
  unsigned short* wtm1 = (unsigned short*)p;   p += (size_t)8192 * 1024 * 2;
  unsigned short* wtm2 = (unsigned short*)p;   p += (size_t)1024 * 4096 * 2;
  unsigned short* hb = (unsigned short*)p;     p += (size_t)8192 * 1024 * 2;
  float* xb = (float*)p;                 p += (size_t)8192 * 1024 * 4;
  char* R1 = p;                          p += (size_t)8192 * 3072 * 4;   // 96 MB
  unsigned short* o_bf = (unsigned short*)p;   p += (size_t)8192 * 1024 * 2;
  unsigned short* qb = (unsigned short*)p;     p += (size_t)8192 * 1024 * 2;
  unsigned short* kvb = (unsigned short*)p;    p += (size_t)2048 * 2048 * 2;
  float* kvf = (float*)p;                p += (size_t)2048 * 2048 * 4;
  // total ~244 MB

  // R1 time-multiplexed:
  float* qkvf = (float*)R1;                     // steps 4-5
  unsigned* Sp = (unsigned*)R1;                 // step 10 (64 MB per q-chunk)
  float* Ubuf = (float*)R1;                     // step 13
  unsigned short* Gbuf = (unsigned short*)(R1 + (size_t)2048 * 8192 * 4);

  // 1. modulation
  k_mod_ada<<<dim3(36, 2), 256, 0, stream>>>(mod, w_ada, b_ada, mb);
  // 2. weight transposes + ctx cast
  k_wt<<<dim3(96, 32), 256, 0, stream>>>(w_qkv, wtqkv, 1024, 3072);
  k_wt<<<dim3(32, 32), 256, 0, stream>>>(w_so, wtso, 1024, 1024);
  k_wt<<<dim3(32, 32), 256, 0, stream>>>(w_q, wtq, 1024, 1024);
  k_wt<<<dim3(64, 32), 256, 0, stream>>>(w_kv, wtkv, 1024, 2048);
  k_wt<<<dim3(32, 32), 256, 0, stream>>>(w_co, wtco, 1024, 1024);
  k_wt<<<dim3(256, 32), 256, 0, stream>>>(w_m1, wtm1, 1024, 8192);
  k_wt<<<dim3(32, 128), 256, 0, stream>>>(w_m2, wtm2, 4096, 1024);
  k_cast_bf<<<2048, 256, 0, stream>>>(ctx, ctxb, 524288);
  // 3. LN1
  k_ln_mod<<<8192, 256, 0, stream>>>(x0, mb, hb, 0, 1);
  // 4. qkv projection
  k_gemm_bf<0, 0><<<dim3(24, 64), 256, 0, stream>>>(hb, wtqkv, b_qkv, qkvf,
                                                    nullptr, nullptr, 8192, 3072, 1024, 0, 0);
  // 5. self-attention
  k_self_attn<<<256, 512, 0, stream>>>(qkvf, o_bf);
  // 6. so proj + residual
  k_gemm_bf<1, 0><<<dim3(8, 64), 256, 0, stream>>>(o_bf, wtso, b_so, xb,
                                                   x0, mb, 8192, 1024, 1024, 2, 0);
  // 7. LN2
  k_ln_mod<<<8192, 256, 0, stream>>>(xb, mb, hb, 3, 4);
  // 8. q projection (bf16 out)
  k_gemm_bf<0, 1><<<dim3(8, 64), 256, 0, stream>>>(hb, wtq, b_q, qb,
                                                   nullptr, nullptr, 8192, 1024, 1024, 0, 0);
  // 9. kv projection (fp32) + bf16 copy for scores
  k_gemm_bf<0, 0><<<dim3(16, 16), 256, 0, stream>>>(ctxb, wtkv, b_kv, kvf,
                                                    nullptr, nullptr, 2048, 2048, 1024, 0, 0);
  k_cast_bf<<<4096, 256, 0, stream>>>(kvf, kvb, 1048576);
  // 10. cross-attn: scores (packed) + wave top-16 + gather, in 8 q-chunks
  for (int q0 = 0; q0 < LSEQ; q0 += 512) {
    k_cross_scores<<<dim3(8, 4, 32), 256, 0, stream>>>(qb, kvb, Sp, q0);
    k_topk_gather<<<4096, 256, 0, stream>>>(Sp, kvf, o_bf, q0);
  }
  // 12. co proj + residual (in-place xb)
  k_gemm_bf<1, 0><<<dim3(8, 64), 256, 0, stream>>>(o_bf, wtco, b_co, xb,
                                                   xb, mb, 8192, 1024, 1024, 5, 0);
  // 13. LN3
  k_ln_mod<<<8192, 256, 0, stream>>>(xb, mb, hb, 6, 7);
  // 14. swiglu chunks
  for (int ch = 0; ch < 4; ++ch) {
    const unsigned short* hA = hb + (size_t)ch * 2048 * 1024;
    k_gemm_bf<0, 0><<<dim3(64, 16), 256, 0, stream>>>(hA, wtm1, b_m1, Ubuf,
                                                      nullptr, nullptr, 2048, 8192, 1024, 0, 0);
    k_silu_mul<<<8192, 256, 0, stream>>>(Ubuf, Gbuf, 2048);
    k_gemm_bf<1, 0><<<dim3(8, 16), 256, 0, stream>>>(Gbuf, wtm2, b_m2,
                                                     out + (size_t)ch * 2048 * 1024,
                                                     xb + (size_t)ch * 2048 * 1024, mb,
                                                     2048, 1024, 4096, 8, ch * 2048);
  }
}

// Round 5
// 1665.342 us; speedup vs baseline: 4.8657x; 1.2196x over previous
//
#include <hip/hip_runtime.h>
#include <cstdint>
#include <cstddef>

#define CDIM 1024
#define HN 16
#define HD 64
#define WINSZ 512
#define SHIFTSZ 256
#define TK 16
#define HIDDIM 4096
#define LSEQ 4096
#define NCOL9 9216
#define LCTX 1024

typedef __bf16 bf16x8 __attribute__((ext_vector_type(8)));
typedef float f32x4 __attribute__((ext_vector_type(4)));
typedef unsigned short u16x8 __attribute__((ext_vector_type(8)));

static __device__ __forceinline__ unsigned short f2bf(float f) {
  unsigned u = __float_as_uint(f);
  unsigned r = (u + 0x7fffu + ((u >> 16) & 1u)) >> 16;
  return (unsigned short)r;
}

// ---------------------------------------------------------------------------
// m = silu(mod) @ w_ada + b_ada      (2 x 9216)
// ---------------------------------------------------------------------------
__global__ __launch_bounds__(256)
void k_mod_ada(const float* __restrict__ mod, const float* __restrict__ w_ada,
               const float* __restrict__ b_ada, float* __restrict__ m_out) {
  __shared__ float sm[CDIM];
  int b = blockIdx.y;
  int t = threadIdx.x;
  for (int k = t; k < CDIM; k += 256) {
    float v = mod[b * CDIM + k];
    sm[k] = v / (1.f + __expf(-v));
  }
  __syncthreads();
  int j = blockIdx.x * 256 + t;
  float acc = b_ada[j];
#pragma unroll 8
  for (int k = 0; k < CDIM; ++k) acc += sm[k] * w_ada[(size_t)k * NCOL9 + j];
  m_out[b * NCOL9 + j] = acc;
}

// ---------------------------------------------------------------------------
// Weight transpose + cast: W[K][N] fp32 -> WT[N][K] bf16 bits
// ---------------------------------------------------------------------------
__global__ __launch_bounds__(256)
void k_wt(const float* __restrict__ W, unsigned short* __restrict__ WT,
          int K, int N) {
  __shared__ float tl[32][33];
  int tx = threadIdx.x & 31, ty = threadIdx.x >> 5;
  int n0 = blockIdx.x * 32, k0 = blockIdx.y * 32;
#pragma unroll
  for (int i = 0; i < 4; ++i)
    tl[ty + i * 8][tx] = W[(size_t)(k0 + ty + i * 8) * N + n0 + tx];
  __syncthreads();
#pragma unroll
  for (int i = 0; i < 4; ++i) {
    int n = ty + i * 8;
    WT[(size_t)(n0 + n) * K + k0 + tx] = f2bf(tl[tx][n]);
  }
}

// fp32 -> bf16 elementwise
__global__ __launch_bounds__(256)
void k_cast_bf(const float* __restrict__ in, unsigned short* __restrict__ o, int n4) {
  int id = blockIdx.x * 256 + threadIdx.x;
  if (id >= n4) return;
  float4 v = ((const float4*)in)[id];
  ushort4 u;
  u.x = f2bf(v.x); u.y = f2bf(v.y); u.z = f2bf(v.z); u.w = f2bf(v.w);
  ((ushort4*)o)[id] = u;
}

// ---------------------------------------------------------------------------
// h = ln(x) * (1 + sc) + sh  -> bf16   (one block per row)
// ---------------------------------------------------------------------------
__global__ __launch_bounds__(256)
void k_ln_mod(const float* __restrict__ x, const float* __restrict__ mbuf,
              unsigned short* __restrict__ h, int shsel, int scsel) {
  __shared__ float ws1[4], ws2[4], sstat[2];
  int row = blockIdx.x;
  int b = row >> 12;
  int t = threadIdx.x;
  const float4* xr = (const float4*)(x + (size_t)row * CDIM);
  float4 v = xr[t];
  float s1 = v.x + v.y + v.z + v.w;
  float s2 = v.x * v.x + v.y * v.y + v.z * v.z + v.w * v.w;
  for (int off = 32; off; off >>= 1) {
    s1 += __shfl_down(s1, off);
    s2 += __shfl_down(s2, off);
  }
  int wid = t >> 6, lane = t & 63;
  if (lane == 0) { ws1[wid] = s1; ws2[wid] = s2; }
  __syncthreads();
  if (t == 0) {
    float a = 0.f, c = 0.f;
    for (int i = 0; i < 4; ++i) { a += ws1[i]; c += ws2[i]; }
    float mean = a * (1.f / CDIM);
    float var = c * (1.f / CDIM) - mean * mean;
    sstat[0] = mean;
    sstat[1] = rsqrtf(var + 1e-6f);
  }
  __syncthreads();
  float mean = sstat[0], rstd = sstat[1];
  const float* sc = mbuf + b * NCOL9 + scsel * CDIM;
  const float* sh = mbuf + b * NCOL9 + shsel * CDIM;
  int c0 = t * 4;
  ushort4 u;
  u.x = f2bf((v.x - mean) * rstd * (1.f + sc[c0 + 0]) + sh[c0 + 0]);
  u.y = f2bf((v.y - mean) * rstd * (1.f + sc[c0 + 1]) + sh[c0 + 1]);
  u.z = f2bf((v.z - mean) * rstd * (1.f + sc[c0 + 2]) + sh[c0 + 2]);
  u.w = f2bf((v.w - mean) * rstd * (1.f + sc[c0 + 3]) + sh[c0 + 3]);
  *(ushort4*)(h + (size_t)row * CDIM + c0) = u;
}

// ---------------------------------------------------------------------------
// bf16 MFMA GEMM: out[M][N] = Abf[M][K] @ WT[N][K]^T + bias
// EPI=1: out = xres + (acc + bias) * g[b, n]   (fp32 out)
// OUTBF=1: bf16 output (no EPI)
// ---------------------------------------------------------------------------
template <int EPI, int OUTBF>
__global__ __launch_bounds__(256)
void k_gemm_bf(const unsigned short* __restrict__ Ab,
               const unsigned short* __restrict__ Bt,
               const float* __restrict__ bias, void* __restrict__ outp,
               const float* __restrict__ xres, const float* __restrict__ mbuf,
               int M, int N, int K, int gsel, int row0) {
  __shared__ unsigned short lsA[128 * 32];
  __shared__ unsigned short lsB[128 * 32];
  int t = threadIdx.x;
  int bm = blockIdx.y, bn = blockIdx.x;
  int l = t & 63, wv = t >> 6;
  int wm = wv >> 1, wn = wv & 1;
  int lane15 = l & 15, hw = l >> 4;

  int d0 = t, d1 = t + 256;
  int r0 = d0 >> 2, sl0 = (d0 & 3) ^ ((d0 >> 3) & 3);
  int r1 = d1 >> 2, sl1 = (d1 & 3) ^ ((d1 >> 3) & 3);
  const unsigned short* a_src0 = Ab + (size_t)(bm * 128 + r0) * K + sl0 * 8;
  const unsigned short* a_src1 = Ab + (size_t)(bm * 128 + r1) * K + sl1 * 8;
  const unsigned short* b_src0 = Bt + (size_t)(bn * 128 + r0) * K + sl0 * 8;
  const unsigned short* b_src1 = Bt + (size_t)(bn * 128 + r1) * K + sl1 * 8;

  f32x4 acc[4][4];
#pragma unroll
  for (int i = 0; i < 4; ++i)
#pragma unroll
    for (int j = 0; j < 4; ++j) acc[i][j] = (f32x4){0.f, 0.f, 0.f, 0.f};

  auto stage = [&](int kt) {
    int ko = kt * 32;
    __builtin_amdgcn_global_load_lds(
        (const __attribute__((address_space(1))) void*)(a_src0 + ko),
        (__attribute__((address_space(3))) void*)(lsA + d0 * 8), 16, 0, 0);
    __builtin_amdgcn_global_load_lds(
        (const __attribute__((address_space(1))) void*)(a_src1 + ko),
        (__attribute__((address_space(3))) void*)(lsA + d1 * 8), 16, 0, 0);
    __builtin_amdgcn_global_load_lds(
        (const __attribute__((address_space(1))) void*)(b_src0 + ko),
        (__attribute__((address_space(3))) void*)(lsB + d0 * 8), 16, 0, 0);
    __builtin_amdgcn_global_load_lds(
        (const __attribute__((address_space(1))) void*)(b_src1 + ko),
        (__attribute__((address_space(3))) void*)(lsB + d1 * 8), 16, 0, 0);
  };

  stage(0);

  int swz = ((lane15 >> 1) & 3) << 4;
  int aoff = (wm * 64 + lane15) * 64 + (((hw << 4) ^ swz));
  int boff = (wn * 64 + lane15) * 64 + (((hw << 4) ^ swz));

  int nk = K >> 5;
  for (int kt = 0; kt < nk; ++kt) {
    __syncthreads();
    bf16x8 af[4], bfr[4];
#pragma unroll
    for (int i = 0; i < 4; ++i) {
      af[i]  = *reinterpret_cast<const bf16x8*>((const char*)lsA + aoff + i * 1024);
      bfr[i] = *reinterpret_cast<const bf16x8*>((const char*)lsB + boff + i * 1024);
    }
#pragma unroll
    for (int mi = 0; mi < 4; ++mi)
#pragma unroll
      for (int ni = 0; ni < 4; ++ni)
        acc[mi][ni] = __builtin_amdgcn_mfma_f32_16x16x32_bf16(
            af[mi], bfr[ni], acc[mi][ni], 0, 0, 0);
    __syncthreads();
    if (kt + 1 < nk) stage(kt + 1);
  }

  const float* g = nullptr;
  if (EPI) g = mbuf + ((size_t)((row0 + bm * 128) >> 12)) * NCOL9 + gsel * CDIM;
#pragma unroll
  for (int ni = 0; ni < 4; ++ni) {
    int gcol = bn * 128 + wn * 64 + ni * 16 + lane15;
    float bs = bias[gcol];
    float gg = EPI ? g[gcol] : 0.f;
#pragma unroll
    for (int mi = 0; mi < 4; ++mi) {
      int grow0 = bm * 128 + wm * 64 + mi * 16 + hw * 4;
      f32x4 v = acc[mi][ni];
#pragma unroll
      for (int rr = 0; rr < 4; ++rr) {
        size_t idx = (size_t)(grow0 + rr) * N + gcol;
        float ov = v[rr] + bs;
        if (EPI) ov = xres[idx] + ov * gg;
        if (OUTBF) ((unsigned short*)outp)[idx] = f2bf(ov);
        else ((float*)outp)[idx] = ov;
      }
    }
  }
}

// ---------------------------------------------------------------------------
// Windowed shifted self-attention, MFMA flash-style.
// Grid: 1024 = b(2) x w(8) x h(16) x qchunk(4); 256 threads = 4 waves.
// Wave owns 32 q-rows. K-tiles of 64. Q/K frags direct from global bf16;
// V transposed into LDS (shared); P through wave-private swizzled LDS.
// Fragment layouts identical to the HW-verified k_gemm_bf.
// ---------------------------------------------------------------------------
__global__ __launch_bounds__(256)
void k_self_attn_mfma(const unsigned short* __restrict__ qkvb,
                      unsigned short* __restrict__ o_buf) {
  __shared__ unsigned short Vt[64 * 64];       // [d][k] swizzled
  __shared__ unsigned short Pl[4][32 * 64];    // per-wave [q][k] swizzled
  int blk = blockIdx.x;
  int qc = blk & 3;
  int h = (blk >> 2) & 15;
  int w = (blk >> 6) & 7;
  int b = blk >> 9;
  int t = threadIdx.x;
  int l = t & 63, wv = t >> 6;
  int lane15 = l & 15, hw = l >> 4;

  const unsigned short* qkvB = qkvb + (size_t)b * LSEQ * 3072;
  int qbase = qc * 128 + wv * 32;

  // Q A-frags: lane holds Q[q = base+mi*16+lane15][k = ks*32+hw*8 .. +8]
  bf16x8 qf[2][2];
#pragma unroll
  for (int mi = 0; mi < 2; ++mi) {
    int p = (w * WINSZ + qbase + mi * 16 + lane15 + SHIFTSZ) & (LSEQ - 1);
    const unsigned short* qp = qkvB + (size_t)p * 3072 + h * HD + hw * 8;
    qf[mi][0] = *(const bf16x8*)(qp);
    qf[mi][1] = *(const bf16x8*)(qp + 32);
  }

  f32x4 oacc[2][4];
#pragma unroll
  for (int i = 0; i < 2; ++i)
#pragma unroll
    for (int j = 0; j < 4; ++j) oacc[i][j] = (f32x4){0.f, 0.f, 0.f, 0.f};
  float mrow[2][4], lrow[2][4];
#pragma unroll
  for (int i = 0; i < 2; ++i)
#pragma unroll
    for (int r = 0; r < 4; ++r) { mrow[i][r] = -1e30f; lrow[i][r] = 0.f; }

  for (int kt = 0; kt < 8; ++kt) {
    __syncthreads();                 // prev tile's Vt fully consumed
    // stage Vt[d][k] = V[k][d], slot XOR-swizzled by row d
#pragma unroll
    for (int i = 0; i < 2; ++i) {
      int idx = t + i * 256;         // 0..511
      int dc = idx & 7, kk = idx >> 3;
      int pv = (w * WINSZ + kt * 64 + kk + SHIFTSZ) & (LSEQ - 1);
      const unsigned short* vp = qkvB + (size_t)pv * 3072 + 2048 + h * HD + dc * 8;
      u16x8 vvec = *(const u16x8*)vp;
#pragma unroll
      for (int j = 0; j < 8; ++j) {
        int d = dc * 8 + j;
        int slot = (kk >> 3) ^ (d & 7) ^ ((d >> 3) & 7);
        Vt[d * 64 + slot * 8 + (kk & 7)] = (unsigned short)vvec[j];
      }
    }

    // S = Q·K^T (K B-frags direct from global, WT-style)
    f32x4 sacc[2][4];
#pragma unroll
    for (int i = 0; i < 2; ++i)
#pragma unroll
      for (int j = 0; j < 4; ++j) sacc[i][j] = (f32x4){0.f, 0.f, 0.f, 0.f};
#pragma unroll
    for (int ks = 0; ks < 2; ++ks) {
      bf16x8 kf[4];
#pragma unroll
      for (int ni = 0; ni < 4; ++ni) {
        int pk = (w * WINSZ + kt * 64 + ni * 16 + lane15 + SHIFTSZ) & (LSEQ - 1);
        kf[ni] = *(const bf16x8*)(qkvB + (size_t)pk * 3072 + CDIM + h * HD + ks * 32 + hw * 8);
      }
#pragma unroll
      for (int mi = 0; mi < 2; ++mi)
#pragma unroll
        for (int ni = 0; ni < 4; ++ni)
          sacc[mi][ni] = __builtin_amdgcn_mfma_f32_16x16x32_bf16(
              qf[mi][ks], kf[ni], sacc[mi][ni], 0, 0, 0);
    }

    // row max of this tile (scaled): rows live at (hw*4+r), cols at lane15+16*ni
    float tm[2][4];
#pragma unroll
    for (int mi = 0; mi < 2; ++mi)
#pragma unroll
      for (int r = 0; r < 4; ++r) {
        float v = fmaxf(fmaxf(sacc[mi][0][r], sacc[mi][1][r]),
                        fmaxf(sacc[mi][2][r], sacc[mi][3][r]));
#pragma unroll
        for (int mk = 1; mk <= 8; mk <<= 1)
          v = fmaxf(v, __shfl_xor(v, mk));
        tm[mi][r] = v * 0.125f;
      }

    // online softmax update
    float scl[2][4];
#pragma unroll
    for (int mi = 0; mi < 2; ++mi)
#pragma unroll
      for (int r = 0; r < 4; ++r) {
        float mnew = fmaxf(mrow[mi][r], tm[mi][r]);
        scl[mi][r] = __expf(mrow[mi][r] - mnew);
        mrow[mi][r] = mnew;
      }

    // P = exp(s*scale - m), write to wave-private swizzled LDS
    float rsum[2][4] = {{0.f, 0.f, 0.f, 0.f}, {0.f, 0.f, 0.f, 0.f}};
#pragma unroll
    for (int mi = 0; mi < 2; ++mi)
#pragma unroll
      for (int ni = 0; ni < 4; ++ni) {
        int k = ni * 16 + lane15;
#pragma unroll
        for (int r = 0; r < 4; ++r) {
          float pe = __expf(sacc[mi][ni][r] * 0.125f - mrow[mi][r]);
          rsum[mi][r] += pe;
          int q = mi * 16 + hw * 4 + r;
          int slot = (k >> 3) ^ (q & 7) ^ ((q >> 3) & 7);
          Pl[wv][q * 64 + slot * 8 + (k & 7)] = f2bf(pe);
        }
      }
#pragma unroll
    for (int mi = 0; mi < 2; ++mi)
#pragma unroll
      for (int r = 0; r < 4; ++r) {
        float v = rsum[mi][r];
#pragma unroll
        for (int mk = 1; mk <= 8; mk <<= 1)
          v += __shfl_xor(v, mk);
        lrow[mi][r] = lrow[mi][r] * scl[mi][r] + v;
#pragma unroll
        for (int nd = 0; nd < 4; ++nd)
          oacc[mi][nd][r] *= scl[mi][r];
      }

    __syncthreads();                 // Vt staged & visible to all waves

    // O += P·V  (A=P from LDS, B=Vt rows from LDS)
#pragma unroll
    for (int ks = 0; ks < 2; ++ks) {
      bf16x8 pa[2], vb[4];
#pragma unroll
      for (int mi = 0; mi < 2; ++mi) {
        int q = mi * 16 + lane15;
        int slot = (ks * 4 + hw) ^ (q & 7) ^ ((q >> 3) & 7);
        pa[mi] = *(const bf16x8*)&Pl[wv][q * 64 + slot * 8];
      }
#pragma unroll
      for (int nd = 0; nd < 4; ++nd) {
        int d = nd * 16 + lane15;
        int slot = (ks * 4 + hw) ^ (d & 7) ^ ((d >> 3) & 7);
        vb[nd] = *(const bf16x8*)&Vt[d * 64 + slot * 8];
      }
#pragma unroll
      for (int mi = 0; mi < 2; ++mi)
#pragma unroll
        for (int nd = 0; nd < 4; ++nd)
          oacc[mi][nd] = __builtin_amdgcn_mfma_f32_16x16x32_bf16(
              pa[mi], vb[nd], oacc[mi][nd], 0, 0, 0);
    }
  }

  // epilogue: O /= l, write bf16 at rolled position
#pragma unroll
  for (int mi = 0; mi < 2; ++mi)
#pragma unroll
    for (int r = 0; r < 4; ++r) {
      float inv = 1.f / lrow[mi][r];
      int wq = qbase + mi * 16 + hw * 4 + r;
      int p = (w * WINSZ + wq + SHIFTSZ) & (LSEQ - 1);
      unsigned short* op = o_buf + ((size_t)(b * LSEQ + p)) * CDIM + h * HD;
#pragma unroll
      for (int nd = 0; nd < 4; ++nd)
        op[nd * 16 + lane15] = f2bf(oacc[mi][nd][r] * inv);
    }
}

// ---------------------------------------------------------------------------
// Cross-attn scores via MFMA, packed epilogue:
// packed = (monotonic_key(s) & 0xFFFFFC00) | (1023 - k)   -> Sp[b][h][ql][k]
// ---------------------------------------------------------------------------
__global__ __launch_bounds__(256)
void k_cross_scores(const unsigned short* __restrict__ qb,
                    const unsigned short* __restrict__ kvb,
                    unsigned* __restrict__ Sp, int q0) {
  __shared__ unsigned short lsA[128 * 64];
  __shared__ unsigned short lsB[128 * 64];
  int t = threadIdx.x;
  int kt = blockIdx.x, qt = blockIdx.y, bh = blockIdx.z;
  int b = bh >> 4, h = bh & 15;
  int l = t & 63, wv = t >> 6;
  int wm = wv >> 1, wn = wv & 1;
  int lane15 = l & 15, hw = l >> 4;

  const unsigned short* Abase = qb + ((size_t)(b * LSEQ + q0 + qt * 128)) * CDIM + h * HD;
  const unsigned short* Bbase = kvb + ((size_t)(b * LCTX + kt * 128)) * 2048 + h * HD;

#pragma unroll
  for (int i = 0; i < 4; ++i) {
    int c = t + i * 256;
    int r = c >> 3, sl = c & 7;
    int gsl = sl ^ (r & 7);
    __builtin_amdgcn_global_load_lds(
        (const __attribute__((address_space(1))) void*)(Abase + (size_t)r * CDIM + gsl * 8),
        (__attribute__((address_space(3))) void*)(lsA + c * 8), 16, 0, 0);
    __builtin_amdgcn_global_load_lds(
        (const __attribute__((address_space(1))) void*)(Bbase + (size_t)r * 2048 + gsl * 8),
        (__attribute__((address_space(3))) void*)(lsB + c * 8), 16, 0, 0);
  }
  __syncthreads();

  f32x4 acc[4][4];
#pragma unroll
  for (int i = 0; i < 4; ++i)
#pragma unroll
    for (int j = 0; j < 4; ++j) acc[i][j] = (f32x4){0.f, 0.f, 0.f, 0.f};

#pragma unroll
  for (int ks = 0; ks < 2; ++ks) {
    bf16x8 af[4], bfr[4];
#pragma unroll
    for (int i = 0; i < 4; ++i) {
      int ar = wm * 64 + i * 16 + lane15;
      int br = wn * 64 + i * 16 + lane15;
      int sa = (ks * 4 + hw) ^ (ar & 7);
      int sb = (ks * 4 + hw) ^ (br & 7);
      af[i]  = *reinterpret_cast<const bf16x8*>((const char*)lsA + ar * 128 + sa * 16);
      bfr[i] = *reinterpret_cast<const bf16x8*>((const char*)lsB + br * 128 + sb * 16);
    }
#pragma unroll
    for (int mi = 0; mi < 4; ++mi)
#pragma unroll
      for (int ni = 0; ni < 4; ++ni)
        acc[mi][ni] = __builtin_amdgcn_mfma_f32_16x16x32_bf16(
            af[mi], bfr[ni], acc[mi][ni], 0, 0, 0);
  }

  size_t obase = (size_t)(bh * 512) * 1024;
#pragma unroll
  for (int ni = 0; ni < 4; ++ni) {
    int kcol = kt * 128 + wn * 64 + ni * 16 + lane15;
#pragma unroll
    for (int mi = 0; mi < 4; ++mi) {
      int qr0 = qt * 128 + wm * 64 + mi * 16 + hw * 4;
#pragma unroll
      for (int rr = 0; rr < 4; ++rr) {
        float s = acc[mi][ni][rr] * 0.125f;
        unsigned u = __float_as_uint(s);
        unsigned key = ((int)u >= 0) ? (u | 0x80000000u) : ~u;
        unsigned pk = (key & 0xFFFFFC00u) | (unsigned)(1023 - kcol);
        Sp[obase + (size_t)(qr0 + rr) * 1024 + kcol] = pk;
      }
    }
  }
}

// ---------------------------------------------------------------------------
// Wave-per-row top-16 (bitonic, packed u32) + softmax + V gather -> bf16.
// ---------------------------------------------------------------------------
__global__ __launch_bounds__(256)
void k_topk_gather(const unsigned* __restrict__ Sp, const float* __restrict__ kvf,
                   unsigned short* __restrict__ o2, int q0) {
  int t = threadIdx.x;
  int lane = t & 63;
  int lr = blockIdx.x * 4 + (t >> 6);
  int b = lr >> 13;
  int h = (lr >> 9) & 15;
  int ql = lr & 511;

  const uint4* sp = (const uint4*)(Sp + (size_t)lr * 1024);
  unsigned v[16];
#pragma unroll
  for (int r = 0; r < 4; ++r) {
    uint4 x = sp[lane + r * 64];
    v[r * 4 + 0] = x.x; v[r * 4 + 1] = x.y; v[r * 4 + 2] = x.z; v[r * 4 + 3] = x.w;
  }

#pragma unroll
  for (int k = 2; k <= 16; k <<= 1) {
#pragma unroll
    for (int j = k >> 1; j > 0; j >>= 1) {
#pragma unroll
      for (int i = 0; i < 16; ++i) {
        int lidx = i ^ j;
        if (lidx > i) {
          unsigned a = v[i], c = v[lidx];
          unsigned hi = a > c ? a : c, lo = a > c ? c : a;
          if ((i & k) == 0) { v[i] = hi; v[lidx] = lo; }
          else { v[i] = lo; v[lidx] = hi; }
        }
      }
    }
  }

#pragma unroll
  for (int st = 0; st < 6; ++st) {
    unsigned pv[16];
#pragma unroll
    for (int i = 0; i < 16; ++i)
      pv[i] = (unsigned)__shfl_xor((int)v[i], 1 << st);
#pragma unroll
    for (int i = 0; i < 16; ++i) {
      unsigned c = pv[15 - i];
      v[i] = v[i] > c ? v[i] : c;
    }
#pragma unroll
    for (int j = 8; j > 0; j >>= 1) {
#pragma unroll
      for (int i = 0; i < 16; ++i) {
        if ((i & j) == 0) {
          int lidx = i | j;
          unsigned a = v[i], c = v[lidx];
          v[i] = a > c ? a : c;
          v[lidx] = a > c ? c : a;
        }
      }
    }
  }

  float sv[16];
  int iv[16];
#pragma unroll
  for (int i = 0; i < 16; ++i) {
    unsigned pk = v[i];
    unsigned key = pk & 0xFFFFFC00u;
    unsigned ub = (key & 0x80000000u) ? (key & 0x7FFFFFFFu) : ~key;
    sv[i] = __uint_as_float(ub);
    iv[i] = 1023 - (int)(pk & 1023u);
  }
  float mx = sv[0];
#pragma unroll
  for (int i = 1; i < 16; ++i) mx = fmaxf(mx, sv[i]);
  float pw[16], sum = 0.f;
#pragma unroll
  for (int i = 0; i < 16; ++i) { pw[i] = __expf(sv[i] - mx); sum += pw[i]; }
  float inv = 1.f / sum;

  const float* vb = kvf + ((size_t)b * LCTX) * 2048 + CDIM + h * HD + lane;
  float o = 0.f;
#pragma unroll
  for (int i = 0; i < 16; ++i) o += pw[i] * vb[(size_t)iv[i] * 2048];

  int q = q0 + ql;
  o2[((size_t)(b * LSEQ + q)) * CDIM + h * HD + lane] = f2bf(o * inv);
}

// ---------------------------------------------------------------------------
// g = silu(u[:, :HID]) * u[:, HID:]  -> bf16
// ---------------------------------------------------------------------------
__global__ __launch_bounds__(256)
void k_silu_mul(const float* __restrict__ U, unsigned short* __restrict__ G, int rows) {
  int id = blockIdx.x * 256 + threadIdx.x;
  int total = rows * (HIDDIM / 4);
  if (id >= total) return;
  int row = id >> 10;
  int c4 = id & 1023;
  const float4* ua = (const float4*)U + (size_t)row * (2 * HIDDIM / 4) + c4;
  float4 a = *ua;
  float4 bb = *(ua + HIDDIM / 4);
  ushort4 u;
  u.x = f2bf(a.x / (1.f + __expf(-a.x)) * bb.x);
  u.y = f2bf(a.y / (1.f + __expf(-a.y)) * bb.y);
  u.z = f2bf(a.z / (1.f + __expf(-a.z)) * bb.z);
  u.w = f2bf(a.w / (1.f + __expf(-a.w)) * bb.w);
  ((ushort4*)G)[(size_t)row * (HIDDIM / 4) + c4] = u;
}

// ---------------------------------------------------------------------------
extern "C" void kernel_launch(void* const* d_in, const int* in_sizes, int n_in,
                              void* d_out, int out_size, void* d_ws, size_t ws_size,
                              hipStream_t stream) {
  const float* x0    = (const float*)d_in[0];
  const float* mod   = (const float*)d_in[1];
  const float* ctx   = (const float*)d_in[2];
  const float* w_ada = (const float*)d_in[3];
  const float* b_ada = (const float*)d_in[4];
  const float* w_qkv = (const float*)d_in[5];
  const float* b_qkv = (const float*)d_in[6];
  const float* w_so  = (const float*)d_in[7];
  const float* b_so  = (const float*)d_in[8];
  const float* w_q   = (const float*)d_in[9];
  const float* b_q   = (const float*)d_in[10];
  const float* w_kv  = (const float*)d_in[11];
  const float* b_kv  = (const float*)d_in[12];
  const float* w_co  = (const float*)d_in[13];
  const float* b_co  = (const float*)d_in[14];
  const float* w_m1  = (const float*)d_in[15];
  const float* b_m1  = (const float*)d_in[16];
  const float* w_m2  = (const float*)d_in[17];
  const float* b_m2  = (const float*)d_in[18];
  float* out = (float*)d_out;

  char* p = (char*)d_ws;
  float* mb = (float*)p;                 p += 18432 * 4;
  unsigned short* ctxb = (unsigned short*)p;   p += (size_t)2048 * 1024 * 2;
  unsigned short* wtqkv = (unsigned short*)p;  p += (size_t)3072 * 1024 * 2;
  unsigned short* wtso = (unsigned short*)p;   p += (size_t)1024 * 1024 * 2;
  unsigned short* wtq = (unsigned short*)p;    p += (size_t)1024 * 1024 * 2;
  unsigned short* wtkv = (unsigned short*)p;   p += (size_t)2048 * 1024 * 2;
  unsigned short* wtco = (unsigned short*)p;   p += (size_t)1024 * 1024 * 2;
  unsigned short* wtm1 = (unsigned short*)p;   p += (size_t)8192 * 1024 * 2;
  unsigned short* wtm2 = (unsigned short*)p;   p += (size_t)1024 * 4096 * 2;
  unsigned short* hb = (unsigned short*)p;     p += (size_t)8192 * 1024 * 2;
  float* xb = (float*)p;                 p += (size_t)8192 * 1024 * 4;
  char* R1 = p;                          p += (size_t)8192 * 3072 * 4;   // 96 MB
  unsigned short* o_bf = (unsigned short*)p;   p += (size_t)8192 * 1024 * 2;
  unsigned short* qb = (unsigned short*)p;     p += (size_t)8192 * 1024 * 2;
  unsigned short* kvb = (unsigned short*)p;    p += (size_t)2048 * 2048 * 2;
  float* kvf = (float*)p;                p += (size_t)2048 * 2048 * 4;

  // R1 time-multiplexed:
  unsigned short* qkvb = (unsigned short*)R1;   // steps 4-5 (48 MB bf16)
  unsigned* Sp = (unsigned*)R1;                 // step 10 (64 MB per q-chunk)
  float* Ubuf = (float*)R1;                     // step 13
  unsigned short* Gbuf = (unsigned short*)(R1 + (size_t)2048 * 8192 * 4);

  // 1. modulation
  k_mod_ada<<<dim3(36, 2), 256, 0, stream>>>(mod, w_ada, b_ada, mb);
  // 2. weight transposes + ctx cast
  k_wt<<<dim3(96, 32), 256, 0, stream>>>(w_qkv, wtqkv, 1024, 3072);
  k_wt<<<dim3(32, 32), 256, 0, stream>>>(w_so, wtso, 1024, 1024);
  k_wt<<<dim3(32, 32), 256, 0, stream>>>(w_q, wtq, 1024, 1024);
  k_wt<<<dim3(64, 32), 256, 0, stream>>>(w_kv, wtkv, 1024, 2048);
  k_wt<<<dim3(32, 32), 256, 0, stream>>>(w_co, wtco, 1024, 1024);
  k_wt<<<dim3(256, 32), 256, 0, stream>>>(w_m1, wtm1, 1024, 8192);
  k_wt<<<dim3(32, 128), 256, 0, stream>>>(w_m2, wtm2, 4096, 1024);
  k_cast_bf<<<2048, 256, 0, stream>>>(ctx, ctxb, 524288);
  // 3. LN1
  k_ln_mod<<<8192, 256, 0, stream>>>(x0, mb, hb, 0, 1);
  // 4. qkv projection (bf16 out)
  k_gemm_bf<0, 1><<<dim3(24, 64), 256, 0, stream>>>(hb, wtqkv, b_qkv, qkvb,
                                                    nullptr, nullptr, 8192, 3072, 1024, 0, 0);
  // 5. self-attention (MFMA)
  k_self_attn_mfma<<<1024, 256, 0, stream>>>(qkvb, o_bf);
  // 6. so proj + residual
  k_gemm_bf<1, 0><<<dim3(8, 64), 256, 0, stream>>>(o_bf, wtso, b_so, xb,
                                                   x0, mb, 8192, 1024, 1024, 2, 0);
  // 7. LN2
  k_ln_mod<<<8192, 256, 0, stream>>>(xb, mb, hb, 3, 4);
  // 8. q projection (bf16 out)
  k_gemm_bf<0, 1><<<dim3(8, 64), 256, 0, stream>>>(hb, wtq, b_q, qb,
                                                   nullptr, nullptr, 8192, 1024, 1024, 0, 0);
  // 9. kv projection (fp32) + bf16 copy for scores
  k_gemm_bf<0, 0><<<dim3(16, 16), 256, 0, stream>>>(ctxb, wtkv, b_kv, kvf,
                                                    nullptr, nullptr, 2048, 2048, 1024, 0, 0);
  k_cast_bf<<<4096, 256, 0, stream>>>(kvf, kvb, 1048576);
  // 10. cross-attn: scores (packed) + wave top-16 + gather, in 8 q-chunks
  for (int q0 = 0; q0 < LSEQ; q0 += 512) {
    k_cross_scores<<<dim3(8, 4, 32), 256, 0, stream>>>(qb, kvb, Sp, q0);
    k_topk_gather<<<4096, 256, 0, stream>>>(Sp, kvf, o_bf, q0);
  }
  // 12. co proj + residual (in-place xb)
  k_gemm_bf<1, 0><<<dim3(8, 64), 256, 0, stream>>>(o_bf, wtco, b_co, xb,
                                                   xb, mb, 8192, 1024, 1024, 5, 0);
  // 13. LN3
  k_ln_mod<<<8192, 256, 0, stream>>>(xb, mb, hb, 6, 7);
  // 14. swiglu chunks
  for (int ch = 0; ch < 4; ++ch) {
    const unsigned short* hA = hb + (size_t)ch * 2048 * 1024;
    k_gemm_bf<0, 0><<<dim3(64, 16), 256, 0, stream>>>(hA, wtm1, b_m1, Ubuf,
                                                      nullptr, nullptr, 2048, 8192, 1024, 0, 0);
    k_silu_mul<<<8192, 256, 0, stream>>>(Ubuf, Gbuf, 2048);
    k_gemm_bf<1, 0><<<dim3(8, 16), 256, 0, stream>>>(Gbuf, wtm2, b_m2,
                                                     out + (size_t)ch * 2048 * 1024,
                                                     xb + (size_t)ch * 2048 * 1024, mb,
                                                     2048, 1024, 4096, 8, ch * 2048);
  }
}

// Round 7
// 1321.421 us; speedup vs baseline: 6.1321x; 1.2603x over previous
//
#include <hip/hip_runtime.h>
#include <cstdint>
#include <cstddef>

#define CDIM 1024
#define HN 16
#define HD 64
#define WINSZ 512
#define SHIFTSZ 256
#define TK 16
#define HIDDIM 4096
#define LSEQ 4096
#define NCOL9 9216
#define LCTX 1024

typedef __bf16 bf16x8 __attribute__((ext_vector_type(8)));
typedef float f32x4 __attribute__((ext_vector_type(4)));
typedef unsigned short u16x8 __attribute__((ext_vector_type(8)));

static __device__ __forceinline__ unsigned short f2bf(float f) {
  unsigned u = __float_as_uint(f);
  unsigned r = (u + 0x7fffu + ((u >> 16) & 1u)) >> 16;
  return (unsigned short)r;
}

// ---------------------------------------------------------------------------
// m = silu(mod) @ w_ada + b_ada      (2 x 9216)
// ---------------------------------------------------------------------------
__global__ __launch_bounds__(256)
void k_mod_ada(const float* __restrict__ mod, const float* __restrict__ w_ada,
               const float* __restrict__ b_ada, float* __restrict__ m_out) {
  __shared__ float sm[CDIM];
  int b = blockIdx.y;
  int t = threadIdx.x;
  for (int k = t; k < CDIM; k += 256) {
    float v = mod[b * CDIM + k];
    sm[k] = v / (1.f + __expf(-v));
  }
  __syncthreads();
  int j = blockIdx.x * 256 + t;
  float acc = b_ada[j];
#pragma unroll 8
  for (int k = 0; k < CDIM; ++k) acc += sm[k] * w_ada[(size_t)k * NCOL9 + j];
  m_out[b * NCOL9 + j] = acc;
}

// ---------------------------------------------------------------------------
// Weight transpose + cast: W[K][N] fp32 -> WT[N][K] bf16 bits
// ---------------------------------------------------------------------------
__global__ __launch_bounds__(256)
void k_wt(const float* __restrict__ W, unsigned short* __restrict__ WT,
          int K, int N) {
  __shared__ float tl[32][33];
  int tx = threadIdx.x & 31, ty = threadIdx.x >> 5;
  int n0 = blockIdx.x * 32, k0 = blockIdx.y * 32;
#pragma unroll
  for (int i = 0; i < 4; ++i)
    tl[ty + i * 8][tx] = W[(size_t)(k0 + ty + i * 8) * N + n0 + tx];
  __syncthreads();
#pragma unroll
  for (int i = 0; i < 4; ++i) {
    int n = ty + i * 8;
    WT[(size_t)(n0 + n) * K + k0 + tx] = f2bf(tl[tx][n]);
  }
}

// ---------------------------------------------------------------------------
// w_m1 transpose with gate-pair interleave:
// WT row n <- W1 column (n&8 ? 4096:0) + ((n>>4)<<3) + (n&7), so a 16-col
// MFMA group holds 8 a-cols and their 8 matching b-cols (pair = lane^8).
// W: [1024][8192] fp32 -> WT: [8192][1024] bf16
// ---------------------------------------------------------------------------
__global__ __launch_bounds__(256)
void k_wt_swi(const float* __restrict__ W, unsigned short* __restrict__ WT) {
  __shared__ float tl[32][33];
  int t = threadIdx.x;
  int tx = t & 15, ty = t >> 4;          // 16 x 16
  int n0 = blockIdx.x * 32;
  int k0 = blockIdx.y * 32;
  int ca = n0 >> 1;
#pragma unroll
  for (int i = 0; i < 2; ++i) {
    int k = ty + i * 16;
    tl[k][tx] = W[(size_t)(k0 + k) * 8192 + ca + tx];
    tl[k][16 + tx] = W[(size_t)(k0 + k) * 8192 + 4096 + ca + tx];
  }
  __syncthreads();
#pragma unroll
  for (int i = 0; i < 4; ++i) {
    int e = t + i * 256;                 // 0..1023
    int n = e >> 5, k = e & 31;
    int c = ((n & 8) ? 16 : 0) + ((n >> 4) << 3) + (n & 7);
    WT[(size_t)(n0 + n) * 1024 + k0 + k] = f2bf(tl[k][c]);
  }
}

// fp32 -> bf16 elementwise
__global__ __launch_bounds__(256)
void k_cast_bf(const float* __restrict__ in, unsigned short* __restrict__ o, int n4) {
  int id = blockIdx.x * 256 + threadIdx.x;
  if (id >= n4) return;
  float4 v = ((const float4*)in)[id];
  ushort4 u;
  u.x = f2bf(v.x); u.y = f2bf(v.y); u.z = f2bf(v.z); u.w = f2bf(v.w);
  ((ushort4*)o)[id] = u;
}

// ---------------------------------------------------------------------------
// h = ln(x) * (1 + sc) + sh  -> bf16   (one block per row)
// ---------------------------------------------------------------------------
__global__ __launch_bounds__(256)
void k_ln_mod(const float* __restrict__ x, const float* __restrict__ mbuf,
              unsigned short* __restrict__ h, int shsel, int scsel) {
  __shared__ float ws1[4], ws2[4], sstat[2];
  int row = blockIdx.x;
  int b = row >> 12;
  int t = threadIdx.x;
  const float4* xr = (const float4*)(x + (size_t)row * CDIM);
  float4 v = xr[t];
  float s1 = v.x + v.y + v.z + v.w;
  float s2 = v.x * v.x + v.y * v.y + v.z * v.z + v.w * v.w;
  for (int off = 32; off; off >>= 1) {
    s1 += __shfl_down(s1, off);
    s2 += __shfl_down(s2, off);
  }
  int wid = t >> 6, lane = t & 63;
  if (lane == 0) { ws1[wid] = s1; ws2[wid] = s2; }
  __syncthreads();
  if (t == 0) {
    float a = 0.f, c = 0.f;
    for (int i = 0; i < 4; ++i) { a += ws1[i]; c += ws2[i]; }
    float mean = a * (1.f / CDIM);
    float var = c * (1.f / CDIM) - mean * mean;
    sstat[0] = mean;
    sstat[1] = rsqrtf(var + 1e-6f);
  }
  __syncthreads();
  float mean = sstat[0], rstd = sstat[1];
  const float* sc = mbuf + b * NCOL9 + scsel * CDIM;
  const float* sh = mbuf + b * NCOL9 + shsel * CDIM;
  int c0 = t * 4;
  ushort4 u;
  u.x = f2bf((v.x - mean) * rstd * (1.f + sc[c0 + 0]) + sh[c0 + 0]);
  u.y = f2bf((v.y - mean) * rstd * (1.f + sc[c0 + 1]) + sh[c0 + 1]);
  u.z = f2bf((v.z - mean) * rstd * (1.f + sc[c0 + 2]) + sh[c0 + 2]);
  u.w = f2bf((v.w - mean) * rstd * (1.f + sc[c0 + 3]) + sh[c0 + 3]);
  *(ushort4*)(h + (size_t)row * CDIM + c0) = u;
}

// ---------------------------------------------------------------------------
// bf16 MFMA GEMM: out[M][N] = Abf[M][K] @ WT[N][K]^T + bias
// EPI=0: fp32 or bf16 (OUTBF) plain out
// EPI=1: out = xres + (acc + bias) * g[b, n]   (fp32 out)
// EPI=2: swiglu-interleaved: pair = lane^8; a-lanes write
//        silu(a)*b -> bf16 G[M][N/2]
// ---------------------------------------------------------------------------
template <int EPI, int OUTBF>
__global__ __launch_bounds__(256)
void k_gemm_bf(const unsigned short* __restrict__ Ab,
               const unsigned short* __restrict__ Bt,
               const float* __restrict__ bias, void* __restrict__ outp,
               const float* __restrict__ xres, const float* __restrict__ mbuf,
               int M, int N, int K, int gsel, int row0) {
  __shared__ unsigned short lsA[128 * 32];
  __shared__ unsigned short lsB[128 * 32];
  int t = threadIdx.x;
  int bm = blockIdx.y, bn = blockIdx.x;
  int l = t & 63, wv = t >> 6;
  int wm = wv >> 1, wn = wv & 1;
  int lane15 = l & 15, hw = l >> 4;

  int d0 = t, d1 = t + 256;
  int r0 = d0 >> 2, sl0 = (d0 & 3) ^ ((d0 >> 3) & 3);
  int r1 = d1 >> 2, sl1 = (d1 & 3) ^ ((d1 >> 3) & 3);
  const unsigned short* a_src0 = Ab + (size_t)(bm * 128 + r0) * K + sl0 * 8;
  const unsigned short* a_src1 = Ab + (size_t)(bm * 128 + r1) * K + sl1 * 8;
  const unsigned short* b_src0 = Bt + (size_t)(bn * 128 + r0) * K + sl0 * 8;
  const unsigned short* b_src1 = Bt + (size_t)(bn * 128 + r1) * K + sl1 * 8;

  f32x4 acc[4][4];
#pragma unroll
  for (int i = 0; i < 4; ++i)
#pragma unroll
    for (int j = 0; j < 4; ++j) acc[i][j] = (f32x4){0.f, 0.f, 0.f, 0.f};

  auto stage = [&](int kt) {
    int ko = kt * 32;
    __builtin_amdgcn_global_load_lds(
        (const __attribute__((address_space(1))) void*)(a_src0 + ko),
        (__attribute__((address_space(3))) void*)(lsA + d0 * 8), 16, 0, 0);
    __builtin_amdgcn_global_load_lds(
        (const __attribute__((address_space(1))) void*)(a_src1 + ko),
        (__attribute__((address_space(3))) void*)(lsA + d1 * 8), 16, 0, 0);
    __builtin_amdgcn_global_load_lds(
        (const __attribute__((address_space(1))) void*)(b_src0 + ko),
        (__attribute__((address_space(3))) void*)(lsB + d0 * 8), 16, 0, 0);
    __builtin_amdgcn_global_load_lds(
        (const __attribute__((address_space(1))) void*)(b_src1 + ko),
        (__attribute__((address_space(3))) void*)(lsB + d1 * 8), 16, 0, 0);
  };

  stage(0);

  int swz = ((lane15 >> 1) & 3) << 4;
  int aoff = (wm * 64 + lane15) * 64 + (((hw << 4) ^ swz));
  int boff = (wn * 64 + lane15) * 64 + (((hw << 4) ^ swz));

  int nk = K >> 5;
  for (int kt = 0; kt < nk; ++kt) {
    __syncthreads();
    bf16x8 af[4], bfr[4];
#pragma unroll
    for (int i = 0; i < 4; ++i) {
      af[i]  = *reinterpret_cast<const bf16x8*>((const char*)lsA + aoff + i * 1024);
      bfr[i] = *reinterpret_cast<const bf16x8*>((const char*)lsB + boff + i * 1024);
    }
#pragma unroll
    for (int mi = 0; mi < 4; ++mi)
#pragma unroll
      for (int ni = 0; ni < 4; ++ni)
        acc[mi][ni] = __builtin_amdgcn_mfma_f32_16x16x32_bf16(
            af[mi], bfr[ni], acc[mi][ni], 0, 0, 0);
    __syncthreads();
    if (kt + 1 < nk) stage(kt + 1);
  }

  if (EPI == 2) {
    // swiglu epilogue: n interleaved a/b by bit3; p = ((n>>4)<<3)|(n&7)
#pragma unroll
    for (int ni = 0; ni < 4; ++ni) {
      int gcol = bn * 128 + wn * 64 + ni * 16 + lane15;
      int pf = ((gcol >> 4) << 3) | (gcol & 7);
      int isb = (gcol >> 3) & 1;
      float bs = bias[isb ? 4096 + pf : pf];
#pragma unroll
      for (int mi = 0; mi < 4; ++mi) {
        int grow0 = bm * 128 + wm * 64 + mi * 16 + hw * 4;
        f32x4 v = acc[mi][ni];
#pragma unroll
        for (int rr = 0; rr < 4; ++rr) {
          float a = v[rr] + bs;
          float pt = __shfl_xor(a, 8);
          if (!isb) {
            float g = a / (1.f + __expf(-a)) * pt;
            ((unsigned short*)outp)[(size_t)(grow0 + rr) * (HIDDIM) + pf] = f2bf(g);
          }
        }
      }
    }
    return;
  }

  const float* g = nullptr;
  if (EPI == 1) g = mbuf + ((size_t)((row0 + bm * 128) >> 12)) * NCOL9 + gsel * CDIM;
#pragma unroll
  for (int ni = 0; ni < 4; ++ni) {
    int gcol = bn * 128 + wn * 64 + ni * 16 + lane15;
    float bs = bias[gcol];
    float gg = (EPI == 1) ? g[gcol] : 0.f;
#pragma unroll
    for (int mi = 0; mi < 4; ++mi) {
      int grow0 = bm * 128 + wm * 64 + mi * 16 + hw * 4;
      f32x4 v = acc[mi][ni];
#pragma unroll
      for (int rr = 0; rr < 4; ++rr) {
        size_t idx = (size_t)(grow0 + rr) * N + gcol;
        float ov = v[rr] + bs;
        if (EPI == 1) ov = xres[idx] + ov * gg;
        if (OUTBF) ((unsigned short*)outp)[idx] = f2bf(ov);
        else ((float*)outp)[idx] = ov;
      }
    }
  }
}

// ---------------------------------------------------------------------------
// Windowed shifted self-attention, MFMA flash-style.
// ---------------------------------------------------------------------------
__global__ __launch_bounds__(256)
void k_self_attn_mfma(const unsigned short* __restrict__ qkvb,
                      unsigned short* __restrict__ o_buf) {
  __shared__ unsigned short Vt[64 * 64];
  __shared__ unsigned short Pl[4][32 * 64];
  int blk = blockIdx.x;
  int qc = blk & 3;
  int h = (blk >> 2) & 15;
  int w = (blk >> 6) & 7;
  int b = blk >> 9;
  int t = threadIdx.x;
  int l = t & 63, wv = t >> 6;
  int lane15 = l & 15, hw = l >> 4;

  const unsigned short* qkvB = qkvb + (size_t)b * LSEQ * 3072;
  int qbase = qc * 128 + wv * 32;

  bf16x8 qf[2][2];
#pragma unroll
  for (int mi = 0; mi < 2; ++mi) {
    int p = (w * WINSZ + qbase + mi * 16 + lane15 + SHIFTSZ) & (LSEQ - 1);
    const unsigned short* qp = qkvB + (size_t)p * 3072 + h * HD + hw * 8;
    qf[mi][0] = *(const bf16x8*)(qp);
    qf[mi][1] = *(const bf16x8*)(qp + 32);
  }

  f32x4 oacc[2][4];
#pragma unroll
  for (int i = 0; i < 2; ++i)
#pragma unroll
    for (int j = 0; j < 4; ++j) oacc[i][j] = (f32x4){0.f, 0.f, 0.f, 0.f};
  float mrow[2][4], lrow[2][4];
#pragma unroll
  for (int i = 0; i < 2; ++i)
#pragma unroll
    for (int r = 0; r < 4; ++r) { mrow[i][r] = -1e30f; lrow[i][r] = 0.f; }

  for (int kt = 0; kt < 8; ++kt) {
    __syncthreads();
#pragma unroll
    for (int i = 0; i < 2; ++i) {
      int idx = t + i * 256;
      int dc = idx & 7, kk = idx >> 3;
      int pv = (w * WINSZ + kt * 64 + kk + SHIFTSZ) & (LSEQ - 1);
      const unsigned short* vp = qkvB + (size_t)pv * 3072 + 2048 + h * HD + dc * 8;
      u16x8 vvec = *(const u16x8*)vp;
#pragma unroll
      for (int j = 0; j < 8; ++j) {
        int d = dc * 8 + j;
        int slot = (kk >> 3) ^ (d & 7) ^ ((d >> 3) & 7);
        Vt[d * 64 + slot * 8 + (kk & 7)] = (unsigned short)vvec[j];
      }
    }

    f32x4 sacc[2][4];
#pragma unroll
    for (int i = 0; i < 2; ++i)
#pragma unroll
      for (int j = 0; j < 4; ++j) sacc[i][j] = (f32x4){0.f, 0.f, 0.f, 0.f};
#pragma unroll
    for (int ks = 0; ks < 2; ++ks) {
      bf16x8 kf[4];
#pragma unroll
      for (int ni = 0; ni < 4; ++ni) {
        int pk = (w * WINSZ + kt * 64 + ni * 16 + lane15 + SHIFTSZ) & (LSEQ - 1);
        kf[ni] = *(const bf16x8*)(qkvB + (size_t)pk * 3072 + CDIM + h * HD + ks * 32 + hw * 8);
      }
#pragma unroll
      for (int mi = 0; mi < 2; ++mi)
#pragma unroll
        for (int ni = 0; ni < 4; ++ni)
          sacc[mi][ni] = __builtin_amdgcn_mfma_f32_16x16x32_bf16(
              qf[mi][ks], kf[ni], sacc[mi][ni], 0, 0, 0);
    }

    float tm[2][4];
#pragma unroll
    for (int mi = 0; mi < 2; ++mi)
#pragma unroll
      for (int r = 0; r < 4; ++r) {
        float v = fmaxf(fmaxf(sacc[mi][0][r], sacc[mi][1][r]),
                        fmaxf(sacc[mi][2][r], sacc[mi][3][r]));
#pragma unroll
        for (int mk = 1; mk <= 8; mk <<= 1)
          v = fmaxf(v, __shfl_xor(v, mk));
        tm[mi][r] = v * 0.125f;
      }

    float scl[2][4];
#pragma unroll
    for (int mi = 0; mi < 2; ++mi)
#pragma unroll
      for (int r = 0; r < 4; ++r) {
        float mnew = fmaxf(mrow[mi][r], tm[mi][r]);
        scl[mi][r] = __expf(mrow[mi][r] - mnew);
        mrow[mi][r] = mnew;
      }

    float rsum[2][4] = {{0.f, 0.f, 0.f, 0.f}, {0.f, 0.f, 0.f, 0.f}};
#pragma unroll
    for (int mi = 0; mi < 2; ++mi)
#pragma unroll
      for (int ni = 0; ni < 4; ++ni) {
        int k = ni * 16 + lane15;
#pragma unroll
        for (int r = 0; r < 4; ++r) {
          float pe = __expf(sacc[mi][ni][r] * 0.125f - mrow[mi][r]);
          rsum[mi][r] += pe;
          int q = mi * 16 + hw * 4 + r;
          int slot = (k >> 3) ^ (q & 7) ^ ((q >> 3) & 7);
          Pl[wv][q * 64 + slot * 8 + (k & 7)] = f2bf(pe);
        }
      }
#pragma unroll
    for (int mi = 0; mi < 2; ++mi)
#pragma unroll
      for (int r = 0; r < 4; ++r) {
        float v = rsum[mi][r];
#pragma unroll
        for (int mk = 1; mk <= 8; mk <<= 1)
          v += __shfl_xor(v, mk);
        lrow[mi][r] = lrow[mi][r] * scl[mi][r] + v;
#pragma unroll
        for (int nd = 0; nd < 4; ++nd)
          oacc[mi][nd][r] *= scl[mi][r];
      }

    __syncthreads();

#pragma unroll
    for (int ks = 0; ks < 2; ++ks) {
      bf16x8 pa[2], vb[4];
#pragma unroll
      for (int mi = 0; mi < 2; ++mi) {
        int q = mi * 16 + lane15;
        int slot = (ks * 4 + hw) ^ (q & 7) ^ ((q >> 3) & 7);
        pa[mi] = *(const bf16x8*)&Pl[wv][q * 64 + slot * 8];
      }
#pragma unroll
      for (int nd = 0; nd < 4; ++nd) {
        int d = nd * 16 + lane15;
        int slot = (ks * 4 + hw) ^ (d & 7) ^ ((d >> 3) & 7);
        vb[nd] = *(const bf16x8*)&Vt[d * 64 + slot * 8];
      }
#pragma unroll
      for (int mi = 0; mi < 2; ++mi)
#pragma unroll
        for (int nd = 0; nd < 4; ++nd)
          oacc[mi][nd] = __builtin_amdgcn_mfma_f32_16x16x32_bf16(
              pa[mi], vb[nd], oacc[mi][nd], 0, 0, 0);
    }
  }

#pragma unroll
  for (int mi = 0; mi < 2; ++mi)
#pragma unroll
    for (int r = 0; r < 4; ++r) {
      float inv = 1.f / lrow[mi][r];
      int wq = qbase + mi * 16 + hw * 4 + r;
      int p = (w * WINSZ + wq + SHIFTSZ) & (LSEQ - 1);
      unsigned short* op = o_buf + ((size_t)(b * LSEQ + p)) * CDIM + h * HD;
#pragma unroll
      for (int nd = 0; nd < 4; ++nd)
        op[nd * 16 + lane15] = f2bf(oacc[mi][nd][r] * inv);
    }
}

// ---------------------------------------------------------------------------
// Cross-attn scores via MFMA, packed epilogue.
// ---------------------------------------------------------------------------
__global__ __launch_bounds__(256)
void k_cross_scores(const unsigned short* __restrict__ qb,
                    const unsigned short* __restrict__ kvb,
                    unsigned* __restrict__ Sp, int q0) {
  __shared__ unsigned short lsA[128 * 64];
  __shared__ unsigned short lsB[128 * 64];
  int t = threadIdx.x;
  int kt = blockIdx.x, qt = blockIdx.y, bh = blockIdx.z;
  int b = bh >> 4, h = bh & 15;
  int l = t & 63, wv = t >> 6;
  int wm = wv >> 1, wn = wv & 1;
  int lane15 = l & 15, hw = l >> 4;

  const unsigned short* Abase = qb + ((size_t)(b * LSEQ + q0 + qt * 128)) * CDIM + h * HD;
  const unsigned short* Bbase = kvb + ((size_t)(b * LCTX + kt * 128)) * 2048 + h * HD;

#pragma unroll
  for (int i = 0; i < 4; ++i) {
    int c = t + i * 256;
    int r = c >> 3, sl = c & 7;
    int gsl = sl ^ (r & 7);
    __builtin_amdgcn_global_load_lds(
        (const __attribute__((address_space(1))) void*)(Abase + (size_t)r * CDIM + gsl * 8),
        (__attribute__((address_space(3))) void*)(lsA + c * 8), 16, 0, 0);
    __builtin_amdgcn_global_load_lds(
        (const __attribute__((address_space(1))) void*)(Bbase + (size_t)r * 2048 + gsl * 8),
        (__attribute__((address_space(3))) void*)(lsB + c * 8), 16, 0, 0);
  }
  __syncthreads();

  f32x4 acc[4][4];
#pragma unroll
  for (int i = 0; i < 4; ++i)
#pragma unroll
    for (int j = 0; j < 4; ++j) acc[i][j] = (f32x4){0.f, 0.f, 0.f, 0.f};

#pragma unroll
  for (int ks = 0; ks < 2; ++ks) {
    bf16x8 af[4], bfr[4];
#pragma unroll
    for (int i = 0; i < 4; ++i) {
      int ar = wm * 64 + i * 16 + lane15;
      int br = wn * 64 + i * 16 + lane15;
      int sa = (ks * 4 + hw) ^ (ar & 7);
      int sb = (ks * 4 + hw) ^ (br & 7);
      af[i]  = *reinterpret_cast<const bf16x8*>((const char*)lsA + ar * 128 + sa * 16);
      bfr[i] = *reinterpret_cast<const bf16x8*>((const char*)lsB + br * 128 + sb * 16);
    }
#pragma unroll
    for (int mi = 0; mi < 4; ++mi)
#pragma unroll
      for (int ni = 0; ni < 4; ++ni)
        acc[mi][ni] = __builtin_amdgcn_mfma_f32_16x16x32_bf16(
            af[mi], bfr[ni], acc[mi][ni], 0, 0, 0);
  }

  size_t obase = (size_t)(bh * 512) * 1024;
#pragma unroll
  for (int ni = 0; ni < 4; ++ni) {
    int kcol = kt * 128 + wn * 64 + ni * 16 + lane15;
#pragma unroll
    for (int mi = 0; mi < 4; ++mi) {
      int qr0 = qt * 128 + wm * 64 + mi * 16 + hw * 4;
#pragma unroll
      for (int rr = 0; rr < 4; ++rr) {
        float s = acc[mi][ni][rr] * 0.125f;
        unsigned u = __float_as_uint(s);
        unsigned key = ((int)u >= 0) ? (u | 0x80000000u) : ~u;
        unsigned pk = (key & 0xFFFFFC00u) | (unsigned)(1023 - kcol);
        Sp[obase + (size_t)(qr0 + rr) * 1024 + kcol] = pk;
      }
    }
  }
}

// ---------------------------------------------------------------------------
// Wave-per-row top-16 (bitonic, packed u32) + softmax + V gather -> bf16.
// ---------------------------------------------------------------------------
__global__ __launch_bounds__(256)
void k_topk_gather(const unsigned* __restrict__ Sp, const float* __restrict__ kvf,
                   unsigned short* __restrict__ o2, int q0) {
  int t = threadIdx.x;
  int lane = t & 63;
  int lr = blockIdx.x * 4 + (t >> 6);
  int b = lr >> 13;
  int h = (lr >> 9) & 15;
  int ql = lr & 511;

  const uint4* sp = (const uint4*)(Sp + (size_t)lr * 1024);
  unsigned v[16];
#pragma unroll
  for (int r = 0; r < 4; ++r) {
    uint4 x = sp[lane + r * 64];
    v[r * 4 + 0] = x.x; v[r * 4 + 1] = x.y; v[r * 4 + 2] = x.z; v[r * 4 + 3] = x.w;
  }

#pragma unroll
  for (int k = 2; k <= 16; k <<= 1) {
#pragma unroll
    for (int j = k >> 1; j > 0; j >>= 1) {
#pragma unroll
      for (int i = 0; i < 16; ++i) {
        int lidx = i ^ j;
        if (lidx > i) {
          unsigned a = v[i], c = v[lidx];
          unsigned hi = a > c ? a : c, lo = a > c ? c : a;
          if ((i & k) == 0) { v[i] = hi; v[lidx] = lo; }
          else { v[i] = lo; v[lidx] = hi; }
        }
      }
    }
  }

#pragma unroll
  for (int st = 0; st < 6; ++st) {
    unsigned pv[16];
#pragma unroll
    for (int i = 0; i < 16; ++i)
      pv[i] = (unsigned)__shfl_xor((int)v[i], 1 << st);
#pragma unroll
    for (int i = 0; i < 16; ++i) {
      unsigned c = pv[15 - i];
      v[i] = v[i] > c ? v[i] : c;
    }
#pragma unroll
    for (int j = 8; j > 0; j >>= 1) {
#pragma unroll
      for (int i = 0; i < 16; ++i) {
        if ((i & j) == 0) {
          int lidx = i | j;
          unsigned a = v[i], c = v[lidx];
          v[i] = a > c ? a : c;
          v[lidx] = a > c ? c : a;
        }
      }
    }
  }

  float sv[16];
  int iv[16];
#pragma unroll
  for (int i = 0; i < 16; ++i) {
    unsigned pk = v[i];
    unsigned key = pk & 0xFFFFFC00u;
    unsigned ub = (key & 0x80000000u) ? (key & 0x7FFFFFFFu) : ~key;
    sv[i] = __uint_as_float(ub);
    iv[i] = 1023 - (int)(pk & 1023u);
  }
  float mx = sv[0];
#pragma unroll
  for (int i = 1; i < 16; ++i) mx = fmaxf(mx, sv[i]);
  float pw[16], sum = 0.f;
#pragma unroll
  for (int i = 0; i < 16; ++i) { pw[i] = __expf(sv[i] - mx); sum += pw[i]; }
  float inv = 1.f / sum;

  const float* vb = kvf + ((size_t)b * LCTX) * 2048 + CDIM + h * HD + lane;
  float o = 0.f;
#pragma unroll
  for (int i = 0; i < 16; ++i) o += pw[i] * vb[(size_t)iv[i] * 2048];

  int q = q0 + ql;
  o2[((size_t)(b * LSEQ + q)) * CDIM + h * HD + lane] = f2bf(o * inv);
}

// ---------------------------------------------------------------------------
extern "C" void kernel_launch(void* const* d_in, const int* in_sizes, int n_in,
                              void* d_out, int out_size, void* d_ws, size_t ws_size,
                              hipStream_t stream) {
  const float* x0    = (const float*)d_in[0];
  const float* mod   = (const float*)d_in[1];
  const float* ctx   = (const float*)d_in[2];
  const float* w_ada = (const float*)d_in[3];
  const float* b_ada = (const float*)d_in[4];
  const float* w_qkv = (const float*)d_in[5];
  const float* b_qkv = (const float*)d_in[6];
  const float* w_so  = (const float*)d_in[7];
  const float* b_so  = (const float*)d_in[8];
  const float* w_q   = (const float*)d_in[9];
  const float* b_q   = (const float*)d_in[10];
  const float* w_kv  = (const float*)d_in[11];
  const float* b_kv  = (const float*)d_in[12];
  const float* w_co  = (const float*)d_in[13];
  const float* b_co  = (const float*)d_in[14];
  const float* w_m1  = (const float*)d_in[15];
  const float* b_m1  = (const float*)d_in[16];
  const float* w_m2  = (const float*)d_in[17];
  const float* b_m2  = (const float*)d_in[18];
  float* out = (float*)d_out;

  char* p = (char*)d_ws;
  float* mb = (float*)p;                 p += 18432 * 4;
  unsigned short* ctxb = (unsigned short*)p;   p += (size_t)2048 * 1024 * 2;
  unsigned short* wtqkv = (unsigned short*)p;  p += (size_t)3072 * 1024 * 2;
  unsigned short* wtso = (unsigned short*)p;   p += (size_t)1024 * 1024 * 2;
  unsigned short* wtq = (unsigned short*)p;    p += (size_t)1024 * 1024 * 2;
  unsigned short* wtkv = (unsigned short*)p;   p += (size_t)2048 * 1024 * 2;
  unsigned short* wtco = (unsigned short*)p;   p += (size_t)1024 * 1024 * 2;
  unsigned short* wtm1 = (unsigned short*)p;   p += (size_t)8192 * 1024 * 2;
  unsigned short* wtm2 = (unsigned short*)p;   p += (size_t)1024 * 4096 * 2;
  unsigned short* hb = (unsigned short*)p;     p += (size_t)8192 * 1024 * 2;
  float* xb = (float*)p;                 p += (size_t)8192 * 1024 * 4;
  char* R1 = p;                          p += (size_t)8192 * 3072 * 4;   // 96 MB
  unsigned short* o_bf = (unsigned short*)p;   p += (size_t)8192 * 1024 * 2;
  unsigned short* qb = (unsigned short*)p;     p += (size_t)8192 * 1024 * 2;
  unsigned short* kvb = (unsigned short*)p;    p += (size_t)2048 * 2048 * 2;
  float* kvf = (float*)p;                p += (size_t)2048 * 2048 * 4;

  // R1 time-multiplexed:
  unsigned short* qkvb = (unsigned short*)R1;   // steps 4-5 (48 MB bf16)
  unsigned* Sp = (unsigned*)R1;                 // step 10 (64 MB per q-chunk)
  unsigned short* Gbuf = (unsigned short*)R1;   // step 14 (67 MB bf16)

  // 1. modulation
  k_mod_ada<<<dim3(36, 2), 256, 0, stream>>>(mod, w_ada, b_ada, mb);
  // 2. weight transposes + ctx cast
  k_wt<<<dim3(96, 32), 256, 0, stream>>>(w_qkv, wtqkv, 1024, 3072);
  k_wt<<<dim3(32, 32), 256, 0, stream>>>(w_so, wtso, 1024, 1024);
  k_wt<<<dim3(32, 32), 256, 0, stream>>>(w_q, wtq, 1024, 1024);
  k_wt<<<dim3(64, 32), 256, 0, stream>>>(w_kv, wtkv, 1024, 2048);
  k_wt<<<dim3(32, 32), 256, 0, stream>>>(w_co, wtco, 1024, 1024);
  k_wt_swi<<<dim3(256, 32), 256, 0, stream>>>(w_m1, wtm1);
  k_wt<<<dim3(32, 128), 256, 0, stream>>>(w_m2, wtm2, 4096, 1024);
  k_cast_bf<<<2048, 256, 0, stream>>>(ctx, ctxb, 524288);
  // 3. LN1
  k_ln_mod<<<8192, 256, 0, stream>>>(x0, mb, hb, 0, 1);
  // 4. qkv projection (bf16 out)
  k_gemm_bf<0, 1><<<dim3(24, 64), 256, 0, stream>>>(hb, wtqkv, b_qkv, qkvb,
                                                    nullptr, nullptr, 8192, 3072, 1024, 0, 0);
  // 5. self-attention (MFMA)
  k_self_attn_mfma<<<1024, 256, 0, stream>>>(qkvb, o_bf);
  // 6. so proj + residual
  k_gemm_bf<1, 0><<<dim3(8, 64), 256, 0, stream>>>(o_bf, wtso, b_so, xb,
                                                   x0, mb, 8192, 1024, 1024, 2, 0);
  // 7. LN2
  k_ln_mod<<<8192, 256, 0, stream>>>(xb, mb, hb, 3, 4);
  // 8. q projection (bf16 out)
  k_gemm_bf<0, 1><<<dim3(8, 64), 256, 0, stream>>>(hb, wtq, b_q, qb,
                                                   nullptr, nullptr, 8192, 1024, 1024, 0, 0);
  // 9. kv projection (fp32) + bf16 copy for scores
  k_gemm_bf<0, 0><<<dim3(16, 16), 256, 0, stream>>>(ctxb, wtkv, b_kv, kvf,
                                                    nullptr, nullptr, 2048, 2048, 1024, 0, 0);
  k_cast_bf<<<4096, 256, 0, stream>>>(kvf, kvb, 1048576);
  // 10. cross-attn: scores (packed) + wave top-16 + gather, in 8 q-chunks
  for (int q0 = 0; q0 < LSEQ; q0 += 512) {
    k_cross_scores<<<dim3(8, 4, 32), 256, 0, stream>>>(qb, kvb, Sp, q0);
    k_topk_gather<<<4096, 256, 0, stream>>>(Sp, kvf, o_bf, q0);
  }
  // 12. co proj + residual (in-place xb)
  k_gemm_bf<1, 0><<<dim3(8, 64), 256, 0, stream>>>(o_bf, wtco, b_co, xb,
                                                   xb, mb, 8192, 1024, 1024, 5, 0);
  // 13. LN3
  k_ln_mod<<<8192, 256, 0, stream>>>(xb, mb, hb, 6, 7);
  // 14. swiglu: fused m1 (silu-gate epilogue) + single m2
  k_gemm_bf<2, 0><<<dim3(64, 64), 256, 0, stream>>>(hb, wtm1, b_m1, Gbuf,
                                                    nullptr, nullptr, 8192, 8192, 1024, 0, 0);
  k_gemm_bf<1, 0><<<dim3(8, 64), 256, 0, stream>>>(Gbuf, wtm2, b_m2, out,
                                                   xb, mb, 8192, 1024, 4096, 8, 0);
}

// Round 8
// 1277.885 us; speedup vs baseline: 6.3410x; 1.0341x over previous
//
#include <hip/hip_runtime.h>
#include <cstdint>
#include <cstddef>

#define CDIM 1024
#define HN 16
#define HD 64
#define WINSZ 512
#define SHIFTSZ 256
#define TK 16
#define HIDDIM 4096
#define LSEQ 4096
#define NCOL9 9216
#define LCTX 1024

typedef __bf16 bf16x8 __attribute__((ext_vector_type(8)));
typedef float f32x4 __attribute__((ext_vector_type(4)));
typedef unsigned short u16x8 __attribute__((ext_vector_type(8)));

static __device__ __forceinline__ unsigned short f2bf(float f) {
  unsigned u = __float_as_uint(f);
  unsigned r = (u + 0x7fffu + ((u >> 16) & 1u)) >> 16;
  return (unsigned short)r;
}

// ---------------------------------------------------------------------------
// m = silu(mod) @ w_ada + b_ada      (2 x 9216)
// ---------------------------------------------------------------------------
__global__ __launch_bounds__(256)
void k_mod_ada(const float* __restrict__ mod, const float* __restrict__ w_ada,
               const float* __restrict__ b_ada, float* __restrict__ m_out) {
  __shared__ float sm[CDIM];
  int b = blockIdx.y;
  int t = threadIdx.x;
  for (int k = t; k < CDIM; k += 256) {
    float v = mod[b * CDIM + k];
    sm[k] = v / (1.f + __expf(-v));
  }
  __syncthreads();
  int j = blockIdx.x * 256 + t;
  float acc = b_ada[j];
#pragma unroll 8
  for (int k = 0; k < CDIM; ++k) acc += sm[k] * w_ada[(size_t)k * NCOL9 + j];
  m_out[b * NCOL9 + j] = acc;
}

// ---------------------------------------------------------------------------
// Weight transpose + cast: W[K][N] fp32 -> WT[N][K] bf16 bits
// ---------------------------------------------------------------------------
__global__ __launch_bounds__(256)
void k_wt(const float* __restrict__ W, unsigned short* __restrict__ WT,
          int K, int N) {
  __shared__ float tl[32][33];
  int tx = threadIdx.x & 31, ty = threadIdx.x >> 5;
  int n0 = blockIdx.x * 32, k0 = blockIdx.y * 32;
#pragma unroll
  for (int i = 0; i < 4; ++i)
    tl[ty + i * 8][tx] = W[(size_t)(k0 + ty + i * 8) * N + n0 + tx];
  __syncthreads();
#pragma unroll
  for (int i = 0; i < 4; ++i) {
    int n = ty + i * 8;
    WT[(size_t)(n0 + n) * K + k0 + tx] = f2bf(tl[tx][n]);
  }
}

// ---------------------------------------------------------------------------
// w_m1 transpose with gate-pair interleave (pair = lane^8).
// W: [1024][8192] fp32 -> WT: [8192][1024] bf16
// ---------------------------------------------------------------------------
__global__ __launch_bounds__(256)
void k_wt_swi(const float* __restrict__ W, unsigned short* __restrict__ WT) {
  __shared__ float tl[32][33];
  int t = threadIdx.x;
  int tx = t & 15, ty = t >> 4;          // 16 x 16
  int n0 = blockIdx.x * 32;
  int k0 = blockIdx.y * 32;
  int ca = n0 >> 1;
#pragma unroll
  for (int i = 0; i < 2; ++i) {
    int k = ty + i * 16;
    tl[k][tx] = W[(size_t)(k0 + k) * 8192 + ca + tx];
    tl[k][16 + tx] = W[(size_t)(k0 + k) * 8192 + 4096 + ca + tx];
  }
  __syncthreads();
#pragma unroll
  for (int i = 0; i < 4; ++i) {
    int e = t + i * 256;                 // 0..1023
    int n = e >> 5, k = e & 31;
    int c = ((n & 8) ? 16 : 0) + ((n >> 4) << 3) + (n & 7);
    WT[(size_t)(n0 + n) * 1024 + k0 + k] = f2bf(tl[k][c]);
  }
}

// fp32 -> bf16 elementwise
__global__ __launch_bounds__(256)
void k_cast_bf(const float* __restrict__ in, unsigned short* __restrict__ o, int n4) {
  int id = blockIdx.x * 256 + threadIdx.x;
  if (id >= n4) return;
  float4 v = ((const float4*)in)[id];
  ushort4 u;
  u.x = f2bf(v.x); u.y = f2bf(v.y); u.z = f2bf(v.z); u.w = f2bf(v.w);
  ((ushort4*)o)[id] = u;
}

// ---------------------------------------------------------------------------
// h = ln(x) * (1 + sc) + sh  -> bf16   (one block per row)
// ---------------------------------------------------------------------------
__global__ __launch_bounds__(256)
void k_ln_mod(const float* __restrict__ x, const float* __restrict__ mbuf,
              unsigned short* __restrict__ h, int shsel, int scsel) {
  __shared__ float ws1[4], ws2[4], sstat[2];
  int row = blockIdx.x;
  int b = row >> 12;
  int t = threadIdx.x;
  const float4* xr = (const float4*)(x + (size_t)row * CDIM);
  float4 v = xr[t];
  float s1 = v.x + v.y + v.z + v.w;
  float s2 = v.x * v.x + v.y * v.y + v.z * v.z + v.w * v.w;
  for (int off = 32; off; off >>= 1) {
    s1 += __shfl_down(s1, off);
    s2 += __shfl_down(s2, off);
  }
  int wid = t >> 6, lane = t & 63;
  if (lane == 0) { ws1[wid] = s1; ws2[wid] = s2; }
  __syncthreads();
  if (t == 0) {
    float a = 0.f, c = 0.f;
    for (int i = 0; i < 4; ++i) { a += ws1[i]; c += ws2[i]; }
    float mean = a * (1.f / CDIM);
    float var = c * (1.f / CDIM) - mean * mean;
    sstat[0] = mean;
    sstat[1] = rsqrtf(var + 1e-6f);
  }
  __syncthreads();
  float mean = sstat[0], rstd = sstat[1];
  const float* sc = mbuf + b * NCOL9 + scsel * CDIM;
  const float* sh = mbuf + b * NCOL9 + shsel * CDIM;
  int c0 = t * 4;
  ushort4 u;
  u.x = f2bf((v.x - mean) * rstd * (1.f + sc[c0 + 0]) + sh[c0 + 0]);
  u.y = f2bf((v.y - mean) * rstd * (1.f + sc[c0 + 1]) + sh[c0 + 1]);
  u.z = f2bf((v.z - mean) * rstd * (1.f + sc[c0 + 2]) + sh[c0 + 2]);
  u.w = f2bf((v.w - mean) * rstd * (1.f + sc[c0 + 3]) + sh[c0 + 3]);
  *(ushort4*)(h + (size_t)row * CDIM + c0) = u;
}

// ---------------------------------------------------------------------------
// bf16 MFMA GEMM: out[M][N] = Abf[M][K] @ WT[N][K]^T + bias
// BK=64 ([128][64] tiles, slot-XOR-by-row&7 swizzle, 32 MFMA per barrier
// pair — halves barrier-drain events vs BK=32; pattern cloned from the
// HW-proven k_cross_scores).
// EPI=0: fp32 or bf16 (OUTBF) plain out
// EPI=1: out = xres + (acc + bias) * g[b, n]   (fp32 out)
// EPI=2: swiglu-interleaved: pair = lane^8; a-lanes write silu(a)*b -> bf16
// ---------------------------------------------------------------------------
template <int EPI, int OUTBF>
__global__ __launch_bounds__(256)
void k_gemm_bf(const unsigned short* __restrict__ Ab,
               const unsigned short* __restrict__ Bt,
               const float* __restrict__ bias, void* __restrict__ outp,
               const float* __restrict__ xres, const float* __restrict__ mbuf,
               int M, int N, int K, int gsel, int row0) {
  __shared__ unsigned short lsA[128 * 64];
  __shared__ unsigned short lsB[128 * 64];
  int t = threadIdx.x;
  int bm = blockIdx.y, bn = blockIdx.x;
  int l = t & 63, wv = t >> 6;
  int wm = wv >> 1, wn = wv & 1;
  int lane15 = l & 15, hw = l >> 4;

  // staging: 4 chunks of 16B per thread per matrix per K-tile of 64
  const unsigned short* a_srcs[4];
  const unsigned short* b_srcs[4];
  int cdst[4];
#pragma unroll
  for (int i = 0; i < 4; ++i) {
    int c = t + i * 256;                 // 0..1023
    int r = c >> 3, sl = c & 7;
    int gsl = sl ^ (r & 7);
    a_srcs[i] = Ab + (size_t)(bm * 128 + r) * K + gsl * 8;
    b_srcs[i] = Bt + (size_t)(bn * 128 + r) * K + gsl * 8;
    cdst[i] = c * 8;
  }

  f32x4 acc[4][4];
#pragma unroll
  for (int i = 0; i < 4; ++i)
#pragma unroll
    for (int j = 0; j < 4; ++j) acc[i][j] = (f32x4){0.f, 0.f, 0.f, 0.f};

  auto stage = [&](int kt) {
    int ko = kt * 64;
#pragma unroll
    for (int i = 0; i < 4; ++i) {
      __builtin_amdgcn_global_load_lds(
          (const __attribute__((address_space(1))) void*)(a_srcs[i] + ko),
          (__attribute__((address_space(3))) void*)(lsA + cdst[i]), 16, 0, 0);
      __builtin_amdgcn_global_load_lds(
          (const __attribute__((address_space(1))) void*)(b_srcs[i] + ko),
          (__attribute__((address_space(3))) void*)(lsB + cdst[i]), 16, 0, 0);
    }
  };

  stage(0);

  int nk = K >> 6;
  for (int kt = 0; kt < nk; ++kt) {
    __syncthreads();
#pragma unroll
    for (int ks = 0; ks < 2; ++ks) {
      bf16x8 af[4], bfr[4];
#pragma unroll
      for (int i = 0; i < 4; ++i) {
        int ar = wm * 64 + i * 16 + lane15;
        int br = wn * 64 + i * 16 + lane15;
        int sa = (ks * 4 + hw) ^ (ar & 7);
        int sb = (ks * 4 + hw) ^ (br & 7);
        af[i]  = *reinterpret_cast<const bf16x8*>((const char*)lsA + ar * 128 + sa * 16);
        bfr[i] = *reinterpret_cast<const bf16x8*>((const char*)lsB + br * 128 + sb * 16);
      }
#pragma unroll
      for (int mi = 0; mi < 4; ++mi)
#pragma unroll
        for (int ni = 0; ni < 4; ++ni)
          acc[mi][ni] = __builtin_amdgcn_mfma_f32_16x16x32_bf16(
              af[mi], bfr[ni], acc[mi][ni], 0, 0, 0);
    }
    __syncthreads();
    if (kt + 1 < nk) stage(kt + 1);
  }

  if (EPI == 2) {
    // swiglu epilogue: n interleaved a/b by bit3; p = ((n>>4)<<3)|(n&7)
#pragma unroll
    for (int ni = 0; ni < 4; ++ni) {
      int gcol = bn * 128 + wn * 64 + ni * 16 + lane15;
      int pf = ((gcol >> 4) << 3) | (gcol & 7);
      int isb = (gcol >> 3) & 1;
      float bs = bias[isb ? 4096 + pf : pf];
#pragma unroll
      for (int mi = 0; mi < 4; ++mi) {
        int grow0 = bm * 128 + wm * 64 + mi * 16 + hw * 4;
        f32x4 v = acc[mi][ni];
#pragma unroll
        for (int rr = 0; rr < 4; ++rr) {
          float a = v[rr] + bs;
          float pt = __shfl_xor(a, 8);
          if (!isb) {
            float g = a / (1.f + __expf(-a)) * pt;
            ((unsigned short*)outp)[(size_t)(grow0 + rr) * (HIDDIM) + pf] = f2bf(g);
          }
        }
      }
    }
    return;
  }

  const float* g = nullptr;
  if (EPI == 1) g = mbuf + ((size_t)((row0 + bm * 128) >> 12)) * NCOL9 + gsel * CDIM;
#pragma unroll
  for (int ni = 0; ni < 4; ++ni) {
    int gcol = bn * 128 + wn * 64 + ni * 16 + lane15;
    float bs = bias[gcol];
    float gg = (EPI == 1) ? g[gcol] : 0.f;
#pragma unroll
    for (int mi = 0; mi < 4; ++mi) {
      int grow0 = bm * 128 + wm * 64 + mi * 16 + hw * 4;
      f32x4 v = acc[mi][ni];
#pragma unroll
      for (int rr = 0; rr < 4; ++rr) {
        size_t idx = (size_t)(grow0 + rr) * N + gcol;
        float ov = v[rr] + bs;
        if (EPI == 1) ov = xres[idx] + ov * gg;
        if (OUTBF) ((unsigned short*)outp)[idx] = f2bf(ov);
        else ((float*)outp)[idx] = ov;
      }
    }
  }
}

// ---------------------------------------------------------------------------
// Windowed shifted self-attention, MFMA flash-style.
// ---------------------------------------------------------------------------
__global__ __launch_bounds__(256)
void k_self_attn_mfma(const unsigned short* __restrict__ qkvb,
                      unsigned short* __restrict__ o_buf) {
  __shared__ unsigned short Vt[64 * 64];
  __shared__ unsigned short Pl[4][32 * 64];
  int blk = blockIdx.x;
  int qc = blk & 3;
  int h = (blk >> 2) & 15;
  int w = (blk >> 6) & 7;
  int b = blk >> 9;
  int t = threadIdx.x;
  int l = t & 63, wv = t >> 6;
  int lane15 = l & 15, hw = l >> 4;

  const unsigned short* qkvB = qkvb + (size_t)b * LSEQ * 3072;
  int qbase = qc * 128 + wv * 32;

  bf16x8 qf[2][2];
#pragma unroll
  for (int mi = 0; mi < 2; ++mi) {
    int p = (w * WINSZ + qbase + mi * 16 + lane15 + SHIFTSZ) & (LSEQ - 1);
    const unsigned short* qp = qkvB + (size_t)p * 3072 + h * HD + hw * 8;
    qf[mi][0] = *(const bf16x8*)(qp);
    qf[mi][1] = *(const bf16x8*)(qp + 32);
  }

  f32x4 oacc[2][4];
#pragma unroll
  for (int i = 0; i < 2; ++i)
#pragma unroll
    for (int j = 0; j < 4; ++j) oacc[i][j] = (f32x4){0.f, 0.f, 0.f, 0.f};
  float mrow[2][4], lrow[2][4];
#pragma unroll
  for (int i = 0; i < 2; ++i)
#pragma unroll
    for (int r = 0; r < 4; ++r) { mrow[i][r] = -1e30f; lrow[i][r] = 0.f; }

  for (int kt = 0; kt < 8; ++kt) {
    __syncthreads();
#pragma unroll
    for (int i = 0; i < 2; ++i) {
      int idx = t + i * 256;
      int dc = idx & 7, kk = idx >> 3;
      int pv = (w * WINSZ + kt * 64 + kk + SHIFTSZ) & (LSEQ - 1);
      const unsigned short* vp = qkvB + (size_t)pv * 3072 + 2048 + h * HD + dc * 8;
      u16x8 vvec = *(const u16x8*)vp;
#pragma unroll
      for (int j = 0; j < 8; ++j) {
        int d = dc * 8 + j;
        int slot = (kk >> 3) ^ (d & 7) ^ ((d >> 3) & 7);
        Vt[d * 64 + slot * 8 + (kk & 7)] = (unsigned short)vvec[j];
      }
    }

    f32x4 sacc[2][4];
#pragma unroll
    for (int i = 0; i < 2; ++i)
#pragma unroll
      for (int j = 0; j < 4; ++j) sacc[i][j] = (f32x4){0.f, 0.f, 0.f, 0.f};
#pragma unroll
    for (int ks = 0; ks < 2; ++ks) {
      bf16x8 kf[4];
#pragma unroll
      for (int ni = 0; ni < 4; ++ni) {
        int pk = (w * WINSZ + kt * 64 + ni * 16 + lane15 + SHIFTSZ) & (LSEQ - 1);
        kf[ni] = *(const bf16x8*)(qkvB + (size_t)pk * 3072 + CDIM + h * HD + ks * 32 + hw * 8);
      }
#pragma unroll
      for (int mi = 0; mi < 2; ++mi)
#pragma unroll
        for (int ni = 0; ni < 4; ++ni)
          sacc[mi][ni] = __builtin_amdgcn_mfma_f32_16x16x32_bf16(
              qf[mi][ks], kf[ni], sacc[mi][ni], 0, 0, 0);
    }

    float tm[2][4];
#pragma unroll
    for (int mi = 0; mi < 2; ++mi)
#pragma unroll
      for (int r = 0; r < 4; ++r) {
        float v = fmaxf(fmaxf(sacc[mi][0][r], sacc[mi][1][r]),
                        fmaxf(sacc[mi][2][r], sacc[mi][3][r]));
#pragma unroll
        for (int mk = 1; mk <= 8; mk <<= 1)
          v = fmaxf(v, __shfl_xor(v, mk));
        tm[mi][r] = v * 0.125f;
      }

    float scl[2][4];
#pragma unroll
    for (int mi = 0; mi < 2; ++mi)
#pragma unroll
      for (int r = 0; r < 4; ++r) {
        float mnew = fmaxf(mrow[mi][r], tm[mi][r]);
        scl[mi][r] = __expf(mrow[mi][r] - mnew);
        mrow[mi][r] = mnew;
      }

    float rsum[2][4] = {{0.f, 0.f, 0.f, 0.f}, {0.f, 0.f, 0.f, 0.f}};
#pragma unroll
    for (int mi = 0; mi < 2; ++mi)
#pragma unroll
      for (int ni = 0; ni < 4; ++ni) {
        int k = ni * 16 + lane15;
#pragma unroll
        for (int r = 0; r < 4; ++r) {
          float pe = __expf(sacc[mi][ni][r] * 0.125f - mrow[mi][r]);
          rsum[mi][r] += pe;
          int q = mi * 16 + hw * 4 + r;
          int slot = (k >> 3) ^ (q & 7) ^ ((q >> 3) & 7);
          Pl[wv][q * 64 + slot * 8 + (k & 7)] = f2bf(pe);
        }
      }
#pragma unroll
    for (int mi = 0; mi < 2; ++mi)
#pragma unroll
      for (int r = 0; r < 4; ++r) {
        float v = rsum[mi][r];
#pragma unroll
        for (int mk = 1; mk <= 8; mk <<= 1)
          v += __shfl_xor(v, mk);
        lrow[mi][r] = lrow[mi][r] * scl[mi][r] + v;
#pragma unroll
        for (int nd = 0; nd < 4; ++nd)
          oacc[mi][nd][r] *= scl[mi][r];
      }

    __syncthreads();

#pragma unroll
    for (int ks = 0; ks < 2; ++ks) {
      bf16x8 pa[2], vb[4];
#pragma unroll
      for (int mi = 0; mi < 2; ++mi) {
        int q = mi * 16 + lane15;
        int slot = (ks * 4 + hw) ^ (q & 7) ^ ((q >> 3) & 7);
        pa[mi] = *(const bf16x8*)&Pl[wv][q * 64 + slot * 8];
      }
#pragma unroll
      for (int nd = 0; nd < 4; ++nd) {
        int d = nd * 16 + lane15;
        int slot = (ks * 4 + hw) ^ (d & 7) ^ ((d >> 3) & 7);
        vb[nd] = *(const bf16x8*)&Vt[d * 64 + slot * 8];
      }
#pragma unroll
      for (int mi = 0; mi < 2; ++mi)
#pragma unroll
        for (int nd = 0; nd < 4; ++nd)
          oacc[mi][nd] = __builtin_amdgcn_mfma_f32_16x16x32_bf16(
              pa[mi], vb[nd], oacc[mi][nd], 0, 0, 0);
    }
  }

#pragma unroll
  for (int mi = 0; mi < 2; ++mi)
#pragma unroll
    for (int r = 0; r < 4; ++r) {
      float inv = 1.f / lrow[mi][r];
      int wq = qbase + mi * 16 + hw * 4 + r;
      int p = (w * WINSZ + wq + SHIFTSZ) & (LSEQ - 1);
      unsigned short* op = o_buf + ((size_t)(b * LSEQ + p)) * CDIM + h * HD;
#pragma unroll
      for (int nd = 0; nd < 4; ++nd)
        op[nd * 16 + lane15] = f2bf(oacc[mi][nd][r] * inv);
    }
}

// ---------------------------------------------------------------------------
// Cross-attn scores via MFMA, packed epilogue.
// ---------------------------------------------------------------------------
__global__ __launch_bounds__(256)
void k_cross_scores(const unsigned short* __restrict__ qb,
                    const unsigned short* __restrict__ kvb,
                    unsigned* __restrict__ Sp, int q0) {
  __shared__ unsigned short lsA[128 * 64];
  __shared__ unsigned short lsB[128 * 64];
  int t = threadIdx.x;
  int kt = blockIdx.x, qt = blockIdx.y, bh = blockIdx.z;
  int b = bh >> 4, h = bh & 15;
  int l = t & 63, wv = t >> 6;
  int wm = wv >> 1, wn = wv & 1;
  int lane15 = l & 15, hw = l >> 4;

  const unsigned short* Abase = qb + ((size_t)(b * LSEQ + q0 + qt * 128)) * CDIM + h * HD;
  const unsigned short* Bbase = kvb + ((size_t)(b * LCTX + kt * 128)) * 2048 + h * HD;

#pragma unroll
  for (int i = 0; i < 4; ++i) {
    int c = t + i * 256;
    int r = c >> 3, sl = c & 7;
    int gsl = sl ^ (r & 7);
    __builtin_amdgcn_global_load_lds(
        (const __attribute__((address_space(1))) void*)(Abase + (size_t)r * CDIM + gsl * 8),
        (__attribute__((address_space(3))) void*)(lsA + c * 8), 16, 0, 0);
    __builtin_amdgcn_global_load_lds(
        (const __attribute__((address_space(1))) void*)(Bbase + (size_t)r * 2048 + gsl * 8),
        (__attribute__((address_space(3))) void*)(lsB + c * 8), 16, 0, 0);
  }
  __syncthreads();

  f32x4 acc[4][4];
#pragma unroll
  for (int i = 0; i < 4; ++i)
#pragma unroll
    for (int j = 0; j < 4; ++j) acc[i][j] = (f32x4){0.f, 0.f, 0.f, 0.f};

#pragma unroll
  for (int ks = 0; ks < 2; ++ks) {
    bf16x8 af[4], bfr[4];
#pragma unroll
    for (int i = 0; i < 4; ++i) {
      int ar = wm * 64 + i * 16 + lane15;
      int br = wn * 64 + i * 16 + lane15;
      int sa = (ks * 4 + hw) ^ (ar & 7);
      int sb = (ks * 4 + hw) ^ (br & 7);
      af[i]  = *reinterpret_cast<const bf16x8*>((const char*)lsA + ar * 128 + sa * 16);
      bfr[i] = *reinterpret_cast<const bf16x8*>((const char*)lsB + br * 128 + sb * 16);
    }
#pragma unroll
    for (int mi = 0; mi < 4; ++mi)
#pragma unroll
      for (int ni = 0; ni < 4; ++ni)
        acc[mi][ni] = __builtin_amdgcn_mfma_f32_16x16x32_bf16(
            af[mi], bfr[ni], acc[mi][ni], 0, 0, 0);
  }

  size_t obase = (size_t)(bh * 512) * 1024;
#pragma unroll
  for (int ni = 0; ni < 4; ++ni) {
    int kcol = kt * 128 + wn * 64 + ni * 16 + lane15;
#pragma unroll
    for (int mi = 0; mi < 4; ++mi) {
      int qr0 = qt * 128 + wm * 64 + mi * 16 + hw * 4;
#pragma unroll
      for (int rr = 0; rr < 4; ++rr) {
        float s = acc[mi][ni][rr] * 0.125f;
        unsigned u = __float_as_uint(s);
        unsigned key = ((int)u >= 0) ? (u | 0x80000000u) : ~u;
        unsigned pk = (key & 0xFFFFFC00u) | (unsigned)(1023 - kcol);
        Sp[obase + (size_t)(qr0 + rr) * 1024 + kcol] = pk;
      }
    }
  }
}

// ---------------------------------------------------------------------------
// Wave-per-row top-16 (bitonic, packed u32) + softmax + V gather -> bf16.
// ---------------------------------------------------------------------------
__global__ __launch_bounds__(256)
void k_topk_gather(const unsigned* __restrict__ Sp, const float* __restrict__ kvf,
                   unsigned short* __restrict__ o2, int q0) {
  int t = threadIdx.x;
  int lane = t & 63;
  int lr = blockIdx.x * 4 + (t >> 6);
  int b = lr >> 13;
  int h = (lr >> 9) & 15;
  int ql = lr & 511;

  const uint4* sp = (const uint4*)(Sp + (size_t)lr * 1024);
  unsigned v[16];
#pragma unroll
  for (int r = 0; r < 4; ++r) {
    uint4 x = sp[lane + r * 64];
    v[r * 4 + 0] = x.x; v[r * 4 + 1] = x.y; v[r * 4 + 2] = x.z; v[r * 4 + 3] = x.w;
  }

#pragma unroll
  for (int k = 2; k <= 16; k <<= 1) {
#pragma unroll
    for (int j = k >> 1; j > 0; j >>= 1) {
#pragma unroll
      for (int i = 0; i < 16; ++i) {
        int lidx = i ^ j;
        if (lidx > i) {
          unsigned a = v[i], c = v[lidx];
          unsigned hi = a > c ? a : c, lo = a > c ? c : a;
          if ((i & k) == 0) { v[i] = hi; v[lidx] = lo; }
          else { v[i] = lo; v[lidx] = hi; }
        }
      }
    }
  }

#pragma unroll
  for (int st = 0; st < 6; ++st) {
    unsigned pv[16];
#pragma unroll
    for (int i = 0; i < 16; ++i)
      pv[i] = (unsigned)__shfl_xor((int)v[i], 1 << st);
#pragma unroll
    for (int i = 0; i < 16; ++i) {
      unsigned c = pv[15 - i];
      v[i] = v[i] > c ? v[i] : c;
    }
#pragma unroll
    for (int j = 8; j > 0; j >>= 1) {
#pragma unroll
      for (int i = 0; i < 16; ++i) {
        if ((i & j) == 0) {
          int lidx = i | j;
          unsigned a = v[i], c = v[lidx];
          v[i] = a > c ? a : c;
          v[lidx] = a > c ? c : a;
        }
      }
    }
  }

  float sv[16];
  int iv[16];
#pragma unroll
  for (int i = 0; i < 16; ++i) {
    unsigned pk = v[i];
    unsigned key = pk & 0xFFFFFC00u;
    unsigned ub = (key & 0x80000000u) ? (key & 0x7FFFFFFFu) : ~key;
    sv[i] = __uint_as_float(ub);
    iv[i] = 1023 - (int)(pk & 1023u);
  }
  float mx = sv[0];
#pragma unroll
  for (int i = 1; i < 16; ++i) mx = fmaxf(mx, sv[i]);
  float pw[16], sum = 0.f;
#pragma unroll
  for (int i = 0; i < 16; ++i) { pw[i] = __expf(sv[i] - mx); sum += pw[i]; }
  float inv = 1.f / sum;

  const float* vb = kvf + ((size_t)b * LCTX) * 2048 + CDIM + h * HD + lane;
  float o = 0.f;
#pragma unroll
  for (int i = 0; i < 16; ++i) o += pw[i] * vb[(size_t)iv[i] * 2048];

  int q = q0 + ql;
  o2[((size_t)(b * LSEQ + q)) * CDIM + h * HD + lane] = f2bf(o * inv);
}

// ---------------------------------------------------------------------------
extern "C" void kernel_launch(void* const* d_in, const int* in_sizes, int n_in,
                              void* d_out, int out_size, void* d_ws, size_t ws_size,
                              hipStream_t stream) {
  const float* x0    = (const float*)d_in[0];
  const float* mod   = (const float*)d_in[1];
  const float* ctx   = (const float*)d_in[2];
  const float* w_ada = (const float*)d_in[3];
  const float* b_ada = (const float*)d_in[4];
  const float* w_qkv = (const float*)d_in[5];
  const float* b_qkv = (const float*)d_in[6];
  const float* w_so  = (const float*)d_in[7];
  const float* b_so  = (const float*)d_in[8];
  const float* w_q   = (const float*)d_in[9];
  const float* b_q   = (const float*)d_in[10];
  const float* w_kv  = (const float*)d_in[11];
  const float* b_kv  = (const float*)d_in[12];
  const float* w_co  = (const float*)d_in[13];
  const float* b_co  = (const float*)d_in[14];
  const float* w_m1  = (const float*)d_in[15];
  const float* b_m1  = (const float*)d_in[16];
  const float* w_m2  = (const float*)d_in[17];
  const float* b_m2  = (const float*)d_in[18];
  float* out = (float*)d_out;

  char* p = (char*)d_ws;
  float* mb = (float*)p;                 p += 18432 * 4;
  unsigned short* ctxb = (unsigned short*)p;   p += (size_t)2048 * 1024 * 2;
  unsigned short* wtqkv = (unsigned short*)p;  p += (size_t)3072 * 1024 * 2;
  unsigned short* wtso = (unsigned short*)p;   p += (size_t)1024 * 1024 * 2;
  unsigned short* wtq = (unsigned short*)p;    p += (size_t)1024 * 1024 * 2;
  unsigned short* wtkv = (unsigned short*)p;   p += (size_t)2048 * 1024 * 2;
  unsigned short* wtco = (unsigned short*)p;   p += (size_t)1024 * 1024 * 2;
  unsigned short* wtm1 = (unsigned short*)p;   p += (size_t)8192 * 1024 * 2;
  unsigned short* wtm2 = (unsigned short*)p;   p += (size_t)1024 * 4096 * 2;
  unsigned short* hb = (unsigned short*)p;     p += (size_t)8192 * 1024 * 2;
  float* xb = (float*)p;                 p += (size_t)8192 * 1024 * 4;
  char* R1 = p;                          p += (size_t)8192 * 3072 * 4;   // 96 MB
  unsigned short* o_bf = (unsigned short*)p;   p += (size_t)8192 * 1024 * 2;
  unsigned short* qb = (unsigned short*)p;     p += (size_t)8192 * 1024 * 2;
  unsigned short* kvb = (unsigned short*)p;    p += (size_t)2048 * 2048 * 2;
  float* kvf = (float*)p;                p += (size_t)2048 * 2048 * 4;

  // R1 time-multiplexed:
  unsigned short* qkvb = (unsigned short*)R1;   // steps 4-5 (48 MB bf16)
  unsigned* Sp = (unsigned*)R1;                 // step 10 (64 MB per q-chunk)
  unsigned short* Gbuf = (unsigned short*)R1;   // step 14 (67 MB bf16)

  // 1. modulation
  k_mod_ada<<<dim3(36, 2), 256, 0, stream>>>(mod, w_ada, b_ada, mb);
  // 2. weight transposes + ctx cast
  k_wt<<<dim3(96, 32), 256, 0, stream>>>(w_qkv, wtqkv, 1024, 3072);
  k_wt<<<dim3(32, 32), 256, 0, stream>>>(w_so, wtso, 1024, 1024);
  k_wt<<<dim3(32, 32), 256, 0, stream>>>(w_q, wtq, 1024, 1024);
  k_wt<<<dim3(64, 32), 256, 0, stream>>>(w_kv, wtkv, 1024, 2048);
  k_wt<<<dim3(32, 32), 256, 0, stream>>>(w_co, wtco, 1024, 1024);
  k_wt_swi<<<dim3(256, 32), 256, 0, stream>>>(w_m1, wtm1);
  k_wt<<<dim3(32, 128), 256, 0, stream>>>(w_m2, wtm2, 4096, 1024);
  k_cast_bf<<<2048, 256, 0, stream>>>(ctx, ctxb, 524288);
  // 3. LN1
  k_ln_mod<<<8192, 256, 0, stream>>>(x0, mb, hb, 0, 1);
  // 4. qkv projection (bf16 out)
  k_gemm_bf<0, 1><<<dim3(24, 64), 256, 0, stream>>>(hb, wtqkv, b_qkv, qkvb,
                                                    nullptr, nullptr, 8192, 3072, 1024, 0, 0);
  // 5. self-attention (MFMA)
  k_self_attn_mfma<<<1024, 256, 0, stream>>>(qkvb, o_bf);
  // 6. so proj + residual
  k_gemm_bf<1, 0><<<dim3(8, 64), 256, 0, stream>>>(o_bf, wtso, b_so, xb,
                                                   x0, mb, 8192, 1024, 1024, 2, 0);
  // 7. LN2
  k_ln_mod<<<8192, 256, 0, stream>>>(xb, mb, hb, 3, 4);
  // 8. q projection (bf16 out)
  k_gemm_bf<0, 1><<<dim3(8, 64), 256, 0, stream>>>(hb, wtq, b_q, qb,
                                                   nullptr, nullptr, 8192, 1024, 1024, 0, 0);
  // 9. kv projection (fp32) + bf16 copy for scores
  k_gemm_bf<0, 0><<<dim3(16, 16), 256, 0, stream>>>(ctxb, wtkv, b_kv, kvf,
                                                    nullptr, nullptr, 2048, 2048, 1024, 0, 0);
  k_cast_bf<<<4096, 256, 0, stream>>>(kvf, kvb, 1048576);
  // 10. cross-attn: scores (packed) + wave top-16 + gather, in 8 q-chunks
  for (int q0 = 0; q0 < LSEQ; q0 += 512) {
    k_cross_scores<<<dim3(8, 4, 32), 256, 0, stream>>>(qb, kvb, Sp, q0);
    k_topk_gather<<<4096, 256, 0, stream>>>(Sp, kvf, o_bf, q0);
  }
  // 12. co proj + residual (in-place xb)
  k_gemm_bf<1, 0><<<dim3(8, 64), 256, 0, stream>>>(o_bf, wtco, b_co, xb,
                                                   xb, mb, 8192, 1024, 1024, 5, 0);
  // 13. LN3
  k_ln_mod<<<8192, 256, 0, stream>>>(xb, mb, hb, 6, 7);
  // 14. swiglu: fused m1 (silu-gate epilogue) + single m2
  k_gemm_bf<2, 0><<<dim3(64, 64), 256, 0, stream>>>(hb, wtm1, b_m1, Gbuf,
                                                    nullptr, nullptr, 8192, 8192, 1024, 0, 0);
  k_gemm_bf<1, 0><<<dim3(8, 64), 256, 0, stream>>>(Gbuf, wtm2, b_m2, out,
                                                   xb, mb, 8192, 1024, 4096, 8, 0);
}